// Round 1
// baseline (712.542 us; speedup 1.0000x reference)
//
#include <hip/hip_runtime.h>

// ============================================================================
// EncoderLayerWithAttn — B=4, S=1024, D=1024, H=16, dh=64, DFF=4096
// d_out = [ out fp32 (4*1024*1024) | attn_weights fp32 (4*16*1024*1024) ]
//
// Round 0: correctness-first. All GEMMs via mfma_f32_16x16x32_bf16 with
// fp32->bf16 conversion during reg-staged LDS fill. fp32 accumulate.
// Workspace (112 MiB, aliased):
//   region0 [0,64M):   qkv fp32 [4096,3072] (48M) + vt fp32 [64,64,1024] (16M)
//                      ... later reused as h1 fp32 [4096,4096] (64M)
//   region1 [64M,80M): ctx fp32 [4096,1024]
//   region2 [80M,96M): xsum fp32 -> later ffsum fp32
//   region3 [96M,112M): x fp32 (LN1 output, kept for final residual)
// ============================================================================

#define DEVI __device__ __forceinline__

typedef __attribute__((ext_vector_type(4))) float f4;
typedef __attribute__((ext_vector_type(4))) float f32x4;
typedef __attribute__((ext_vector_type(8))) short s8;

DEVI short bf16r(float f) {  // fp32 -> bf16, round-to-nearest-even
  unsigned u = __builtin_bit_cast(unsigned, f);
  unsigned r = (u + 0x7fffu + ((u >> 16) & 1u)) >> 16;
  return (short)(unsigned short)r;
}

DEVI s8 cvt8(f4 a, f4 b) {
  s8 r;
  r[0] = bf16r(a.x); r[1] = bf16r(a.y); r[2] = bf16r(a.z); r[3] = bf16r(a.w);
  r[4] = bf16r(b.x); r[5] = bf16r(b.y); r[6] = bf16r(b.z); r[7] = bf16r(b.w);
  return r;
}

constexpr int BK  = 32;
constexpr int LDT = 40;  // padded LDS row stride (elems): 80 B -> 2-way bank pattern (free)

// Stage a ROWS x 32 fp32 tile into bf16 LDS. ROWS*32/EPT == 256 threads.
template<int ROWS, int EPT>
DEVI void stage_tile(const float* __restrict__ G, long ld, short* S, int k0, int tid) {
  constexpr int TPR = BK / EPT;  // threads per row
  int r = tid / TPR;
  int c = (tid % TPR) * EPT;
  const float* g = G + (long)r * ld + k0 + c;
  f4 v0 = *(const f4*)g;
  f4 v1 = *(const f4*)(g + 4);
  *(s8*)&S[r * LDT + c] = cvt8(v0, v1);
  if constexpr (EPT == 16) {
    f4 v2 = *(const f4*)(g + 8);
    f4 v3 = *(const f4*)(g + 12);
    *(s8*)&S[r * LDT + c + 8] = cvt8(v2, v3);
  }
}

// C[N,M] = A[N,K] @ B[M,K]^T  (+bias[c]) (*qscale if c<qcols) (relu) (+resid)
// Batched via blockIdx.z -> (z/inner, z%inner) with per-level strides.
// Grid: (M/BN, N/BM, batch). 256 threads = 4 waves in 2x2.
template<int BM, int BN>
__global__ __launch_bounds__(256)
void gemm_nt(const float* __restrict__ A, long lda, long sAh, long sAl,
             const float* __restrict__ B, long ldb, long sBh, long sBl,
             float* __restrict__ C, long ldc, long sCh, long sCl,
             int inner,
             const float* __restrict__ bias,
             const float* __restrict__ resid, long ldr,
             int K, int qcols, float qscale, int do_relu)
{
  constexpr int WM = BM / 2, WN = BN / 2, FM = WM / 16, FN = WN / 16;
  constexpr int BEPT = BN * BK / 256;
  __shared__ short As[BM * LDT];
  __shared__ short Bs[BN * LDT];

  int z = blockIdx.z;
  int zh = z / inner, zl = z - zh * inner;
  A += (long)zh * sAh + (long)zl * sAl;
  B += (long)zh * sBh + (long)zl * sBl;
  C += (long)zh * sCh + (long)zl * sCl;

  int row0 = blockIdx.y * BM;
  int col0 = blockIdx.x * BN;
  const float* Ab = A + (long)row0 * lda;
  const float* Bb = B + (long)col0 * ldb;

  int tid = threadIdx.x;
  int lane = tid & 63, w = tid >> 6;
  int wr = w >> 1, wc = w & 1;
  int lrow = lane & 15, lk = (lane >> 4) * 8;

  f32x4 acc[FM][FN] = {};

  for (int k0 = 0; k0 < K; k0 += BK) {
    if (k0) __syncthreads();
    stage_tile<BM, 16>(Ab, lda, As, k0, tid);
    stage_tile<BN, BEPT>(Bb, ldb, Bs, k0, tid);
    __syncthreads();
    s8 af[FM], bfr[FN];
#pragma unroll
    for (int i = 0; i < FM; ++i)
      af[i] = *(const s8*)&As[(wr * WM + i * 16 + lrow) * LDT + lk];
#pragma unroll
    for (int j = 0; j < FN; ++j)
      bfr[j] = *(const s8*)&Bs[(wc * WN + j * 16 + lrow) * LDT + lk];
#pragma unroll
    for (int i = 0; i < FM; ++i)
#pragma unroll
      for (int j = 0; j < FN; ++j)
        acc[i][j] = __builtin_amdgcn_mfma_f32_16x16x32_bf16(af[i], bfr[j], acc[i][j], 0, 0, 0);
  }

  // epilogue: C/D layout col=lane&15, row=(lane>>4)*4+reg  [m89-verified]
#pragma unroll
  for (int i = 0; i < FM; ++i) {
#pragma unroll
    for (int j = 0; j < FN; ++j) {
      int rb = row0 + wr * WM + i * 16 + (lane >> 4) * 4;
      int c  = col0 + wc * WN + j * 16 + (lane & 15);
      float bv = bias ? bias[c] : 0.0f;
      float sc = (c < qcols) ? qscale : 1.0f;
#pragma unroll
      for (int q = 0; q < 4; ++q) {
        float v = (acc[i][j][q] + bv) * sc;
        if (do_relu) v = fmaxf(v, 0.0f);
        long r = rb + q;
        if (resid) v += resid[r * ldr + c];
        C[r * ldc + c] = v;
      }
    }
  }
}

// ---------------------------------------------------------------------------
DEVI float blockSum(float v, float* sh) {
#pragma unroll
  for (int o = 32; o > 0; o >>= 1) v += __shfl_xor(v, o);
  int w = threadIdx.x >> 6;
  __syncthreads();
  if ((threadIdx.x & 63) == 0) sh[w] = v;
  __syncthreads();
  return (sh[0] + sh[1]) + (sh[2] + sh[3]);
}

DEVI float blockMax(float v, float* sh) {
#pragma unroll
  for (int o = 32; o > 0; o >>= 1) v = fmaxf(v, __shfl_xor(v, o));
  int w = threadIdx.x >> 6;
  __syncthreads();
  if ((threadIdx.x & 63) == 0) sh[w] = v;
  __syncthreads();
  return fmaxf(fmaxf(sh[0], sh[1]), fmaxf(sh[2], sh[3]));
}

// softmax over rows of 1024, in place (one block per row)
__global__ __launch_bounds__(256)
void softmax_rows(float* __restrict__ p) {
  __shared__ float sh[4];
  long row = blockIdx.x;
  float* r = p + row * 1024;
  int t = threadIdx.x;
  f4 v = *(const f4*)(r + t * 4);
  float m = fmaxf(fmaxf(v.x, v.y), fmaxf(v.z, v.w));
  m = blockMax(m, sh);
  f4 e;
  e.x = __expf(v.x - m); e.y = __expf(v.y - m);
  e.z = __expf(v.z - m); e.w = __expf(v.w - m);
  float s = (e.x + e.y) + (e.z + e.w);
  s = blockSum(s, sh);
  float inv = 1.0f / s;
  *(f4*)(r + t * 4) = e * inv;
}

// LayerNorm over rows of 1024 (one block per row), eps = 1e-5
__global__ __launch_bounds__(256)
void ln_rows(const float* __restrict__ in, const float* __restrict__ g,
             const float* __restrict__ be, float* __restrict__ out) {
  __shared__ float sh[4];
  long row = blockIdx.x;
  const float* p = in + row * 1024;
  int t = threadIdx.x;
  f4 v = *(const f4*)(p + t * 4);
  float s = (v.x + v.y) + (v.z + v.w);
  s = blockSum(s, sh);
  float mu = s * (1.0f / 1024.0f);
  f4 d = v - mu;
  float s2 = (d.x * d.x + d.y * d.y) + (d.z * d.z + d.w * d.w);
  s2 = blockSum(s2, sh);
  float rs = rsqrtf(s2 * (1.0f / 1024.0f) + 1e-5f);
  f4 gg = *(const f4*)(g + t * 4);
  f4 bb = *(const f4*)(be + t * 4);
  *(f4*)(out + row * 1024 + t * 4) = d * rs * gg + bb;
}

// vt[b,h,d,s] = qkv[b,s, 2048 + h*64 + d]  (64x64 LDS tile transpose)
__global__ __launch_bounds__(256)
void transpose_v(const float* __restrict__ qkv, float* __restrict__ vt) {
  __shared__ float tile[64][65];
  int blk = blockIdx.x;
  int bh = blk >> 4;          // 0..63
  int st = blk & 15;          // s-tile
  int b = bh >> 4, h = bh & 15;
  int s0 = st * 64;
  const float* g = qkv + (long)b * 1024 * 3072 + 2048 + (long)h * 64;
  int lane = threadIdx.x & 63, wv = threadIdx.x >> 6;
#pragma unroll
  for (int j = 0; j < 16; ++j) {
    int s = wv * 16 + j;
    tile[lane][s] = g[(long)(s0 + s) * 3072 + lane];
  }
  __syncthreads();
  float* o = vt + (long)bh * 65536 + s0;
#pragma unroll
  for (int j = 0; j < 16; ++j) {
    int d = wv * 16 + j;
    o[(long)d * 1024 + lane] = tile[d][lane];
  }
}

// ============================================================================
extern "C" void kernel_launch(void* const* d_in, const int* in_sizes, int n_in,
                              void* d_out, int out_size, void* d_ws, size_t ws_size,
                              hipStream_t stream)
{
  (void)in_sizes; (void)n_in; (void)out_size; (void)ws_size;
  const float* src   = (const float*)d_in[0];
  const float* w_in  = (const float*)d_in[1];
  const float* b_in  = (const float*)d_in[2];
  const float* w_out = (const float*)d_in[3];
  const float* b_out = (const float*)d_in[4];
  const float* w1    = (const float*)d_in[5];
  const float* b1    = (const float*)d_in[6];
  const float* w2    = (const float*)d_in[7];
  const float* b2    = (const float*)d_in[8];
  const float* g1    = (const float*)d_in[9];
  const float* be1   = (const float*)d_in[10];
  const float* g2    = (const float*)d_in[11];
  const float* be2   = (const float*)d_in[12];

  float* out   = (float*)d_out;
  float* attnW = out + (long)4 * 1024 * 1024;

  char* ws = (char*)d_ws;
  float* qkv  = (float*)(ws);                       // [4096,3072]
  float* vtb  = (float*)(ws + 50331648);            // [64,64,1024]
  float* h1   = (float*)(ws);                       // [4096,4096] (aliases qkv+vt, dead by then)
  float* ctx  = (float*)(ws + 67108864);            // [4096,1024]
  float* xsum = (float*)(ws + 83886080);            // [4096,1024]
  float* ffs  = (float*)(ws + 83886080);            // aliases xsum (dead by then)
  float* x    = (float*)(ws + 100663296);           // [4096,1024]

  // 1. qkv = src @ w_in^T + b_in ; q-part (cols<1024) scaled by 1/8
  gemm_nt<128, 128><<<dim3(24, 32, 1), 256, 0, stream>>>(
      src, 1024, 0, 0, w_in, 1024, 0, 0, qkv, 3072, 0, 0, 1,
      b_in, nullptr, 0, 1024, 1024, 0.125f, 0);

  // 2. vt[b,h,d,s] = v
  transpose_v<<<dim3(1024), 256, 0, stream>>>(qkv, vtb);

  // 3. scores = q @ k^T  (batched over b,h) -> attn region of d_out (fp32)
  gemm_nt<128, 128><<<dim3(8, 8, 64), 256, 0, stream>>>(
      qkv, 3072, 3145728, 64,
      qkv + 1024, 3072, 3145728, 64,
      attnW, 1024, 16777216, 1048576, 16,
      nullptr, nullptr, 0, 64, 0, 1.0f, 0);

  // 4. softmax rows, in place
  softmax_rows<<<dim3(65536), 256, 0, stream>>>(attnW);

  // 5. ctx[b,s,h,d] = P @ V  (batched; C col-offset h*64 via strides)
  gemm_nt<128, 64><<<dim3(1, 8, 64), 256, 0, stream>>>(
      attnW, 1024, 16777216, 1048576,
      vtb, 1024, 1048576, 65536,
      ctx, 1024, 1048576, 64, 16,
      nullptr, nullptr, 0, 1024, 0, 1.0f, 0);

  // 6. xsum = src + (ctx @ w_out^T + b_out)
  gemm_nt<128, 128><<<dim3(8, 32, 1), 256, 0, stream>>>(
      ctx, 1024, 0, 0, w_out, 1024, 0, 0, xsum, 1024, 0, 0, 1,
      b_out, src, 1024, 1024, 0, 1.0f, 0);

  // 7. x = LN1(xsum)
  ln_rows<<<dim3(4096), 256, 0, stream>>>(xsum, g1, be1, x);

  // 8. h1 = relu(x @ w1^T + b1)
  gemm_nt<128, 128><<<dim3(32, 32, 1), 256, 0, stream>>>(
      x, 1024, 0, 0, w1, 1024, 0, 0, h1, 4096, 0, 0, 1,
      b1, nullptr, 0, 1024, 0, 1.0f, 1);

  // 9. ffs = x + (h1 @ w2^T + b2)
  gemm_nt<128, 128><<<dim3(8, 32, 1), 256, 0, stream>>>(
      h1, 4096, 0, 0, w2, 4096, 0, 0, ffs, 1024, 0, 0, 1,
      b2, x, 1024, 4096, 0, 1.0f, 0);

  // 10. out = LN2(ffs)
  ln_rows<<<dim3(4096), 256, 0, stream>>>(ffs, g2, be2, out);
}

// Round 2
// 435.982 us; speedup vs baseline: 1.6343x; 1.6343x over previous
//
#include <hip/hip_runtime.h>

// ============================================================================
// EncoderLayerWithAttn — B=4, S=1024, D=1024, H=16, dh=64, DFF=4096
// d_out = [ out fp32 (4M) | attn_weights fp32 (64M) ]
//
// Round 1: bf16 everywhere + global_load_lds(16B) GEMMs (m97 structure),
// XOR-swizzled LDS (both-sides), split-K=2 for grid-starved GEMMs with
// combine folded into residual+LN kernels.
//
// Workspace layout (112 MiB, proven safe in round 0):
//   [0,24M):   qkvb bf16 [4096,3072]     -> later h1b bf16 [4096,4096] spans [0,32M)
//   [24,32M):  vtb  bf16 [64][64][1024]
//   [32,40M):  srcb bf16 [4096,1024]
//   [40,64M):  w_in_b(6) w_out_b(2) w1b(8) w2b(8)
//   [64,96M):  P0,P1 fp32 split-K partials (out-proj, then FFN2)
//   [96,104M): ctxb bf16 [4096,1024]
//   [104,112M): xb bf16 [4096,1024] (LN1 out; FFN1 A; LN2 residual)
// ============================================================================

#define DEVI __device__ __forceinline__

typedef __attribute__((ext_vector_type(4))) float f4;
typedef __attribute__((ext_vector_type(4))) float f32x4;
typedef __attribute__((ext_vector_type(8))) short s8;
typedef __attribute__((ext_vector_type(4))) unsigned short us4;
typedef unsigned short u16;

DEVI short bf16r(float f) {  // fp32 -> bf16 RNE
  unsigned u = __builtin_bit_cast(unsigned, f);
  unsigned r = (u + 0x7fffu + ((u >> 16) & 1u)) >> 16;
  return (short)(unsigned short)r;
}
DEVI float bf2f(u16 h) {
  unsigned u = ((unsigned)h) << 16;
  return __builtin_bit_cast(float, u);
}
DEVI s8 cvt8(f4 a, f4 b) {
  s8 r;
  r[0] = bf16r(a.x); r[1] = bf16r(a.y); r[2] = bf16r(a.z); r[3] = bf16r(a.w);
  r[4] = bf16r(b.x); r[5] = bf16r(b.y); r[6] = bf16r(b.z); r[7] = bf16r(b.w);
  return r;
}

DEVI void gload16(const void* g, void* l) {
  __builtin_amdgcn_global_load_lds(
      (const __attribute__((address_space(1))) unsigned int*)g,
      (__attribute__((address_space(3))) unsigned int*)l, 16, 0, 0);
}

// ---------------------------------------------------------------------------
// C[N-rows, M-cols] = A[rows,K] @ B[cols,K]^T ; bf16 MFMA, fp32 acc.
// BK=64. LDS rows are 128 B, XOR-swizzled: physical granule = logical ^ (row&7).
// global_load_lds writes linear LDS; swizzle realized by pre-permuting the
// per-lane GLOBAL source granule (guide G21 / m173).
// A32: A operand is fp32 in memory (reg-staged cvt, swizzled ds_write).
// Batched/split-K via blockIdx.z -> (z/inner, z%inner) strides (elements).
template<int BM, int BN, bool A32, bool OUTBF16>
__global__ __launch_bounds__(256)
void gemm(const void* __restrict__ Ap_, long lda, long sAh, long sAl,
          const u16* __restrict__ Bp_, long ldb, long sBh, long sBl,
          void* __restrict__ Cp_, long ldc, long sCh, long sCl, int inner,
          const float* __restrict__ bias, int K,
          int qcols, float qscale, int do_relu)
{
  constexpr int WM = BM / 2, WN = BN / 2, FM = WM / 16, FN = WN / 16;
  constexpr int CA = BM / 32, CB = BN / 32;  // gload16 calls per wave
  __shared__ __align__(128) short As[BM * 64];
  __shared__ __align__(128) short Bs[BN * 64];

  int z = blockIdx.z, zh = z / inner, zl = z - zh * inner;
  long aoff = (long)zh * sAh + (long)zl * sAl;
  long coff = (long)zh * sCh + (long)zl * sCl;

  int row0 = blockIdx.y * BM, col0 = blockIdx.x * BN;
  int tid = threadIdx.x, lane = tid & 63, w = tid >> 6;
  int wr = w >> 1, wc = w & 1;

  const u16* Bb = Bp_ + (long)zh * sBh + (long)zl * sBl + (long)col0 * ldb;
  const u16* Ab16 = nullptr;
  const float* Ab32 = nullptr;
  if constexpr (A32) Ab32 = (const float*)Ap_ + aoff + (long)row0 * lda;
  else               Ab16 = (const u16*)Ap_ + aoff + (long)row0 * lda;

  f32x4 acc[FM][FN] = {};

  for (int k0 = 0; k0 < K; k0 += 64) {
    if (k0) __syncthreads();
    // ---- stage A ----
    if constexpr (A32) {
      int r = tid >> 1, half = tid & 1;
      const float* gp = Ab32 + (long)r * lda + k0 + half * 32;
      char* lb = (char*)As + r * 128;
#pragma unroll
      for (int gi = 0; gi < 4; ++gi) {
        f4 v0 = *(const f4*)(gp + gi * 8);
        f4 v1 = *(const f4*)(gp + gi * 8 + 4);
        int g = half * 4 + gi;
        *(s8*)(lb + ((g ^ (r & 7)) * 16)) = cvt8(v0, v1);
      }
    } else {
#pragma unroll
      for (int c = 0; c < CA; ++c) {
        int seg = w * CA + c;                 // wave-uniform
        int r = seg * 8 + (lane >> 3);
        int g = (lane & 7) ^ (r & 7);         // pre-swizzled source granule
        gload16(Ab16 + (long)r * lda + k0 + g * 8, (char*)As + seg * 1024);
      }
    }
    // ---- stage B (always bf16) ----
#pragma unroll
    for (int c = 0; c < CB; ++c) {
      int seg = w * CB + c;
      int r = seg * 8 + (lane >> 3);
      int g = (lane & 7) ^ (r & 7);
      gload16(Bb + (long)r * ldb + k0 + g * 8, (char*)Bs + seg * 1024);
    }
    __syncthreads();

    // ---- compute: 2 kk-steps of 16x16x32 ----
#pragma unroll
    for (int kk = 0; kk < 2; ++kk) {
      s8 af[FM], bf[FN];
      int lr = lane & 15, kg = kk * 4 + (lane >> 4);  // logical 16B granule
#pragma unroll
      for (int i = 0; i < FM; ++i) {
        int R = wr * WM + i * 16 + lr;
        af[i] = *(const s8*)((char*)As + R * 128 + ((kg ^ (R & 7)) * 16));
      }
#pragma unroll
      for (int j = 0; j < FN; ++j) {
        int R = wc * WN + j * 16 + lr;
        bf[j] = *(const s8*)((char*)Bs + R * 128 + ((kg ^ (R & 7)) * 16));
      }
#pragma unroll
      for (int i = 0; i < FM; ++i)
#pragma unroll
        for (int j = 0; j < FN; ++j)
          acc[i][j] = __builtin_amdgcn_mfma_f32_16x16x32_bf16(af[i], bf[j], acc[i][j], 0, 0, 0);
    }
  }

  // ---- epilogue: C/D layout col=lane&15, row=(lane>>4)*4+q ----
  float* Cf = (float*)Cp_ + coff;
  u16*   Cb = (u16*)Cp_ + coff;
#pragma unroll
  for (int i = 0; i < FM; ++i) {
#pragma unroll
    for (int j = 0; j < FN; ++j) {
      int rb = row0 + wr * WM + i * 16 + (lane >> 4) * 4;
      int c  = col0 + wc * WN + j * 16 + (lane & 15);
      float bv = bias ? bias[c] : 0.0f;
      float sc = (c < qcols) ? qscale : 1.0f;
#pragma unroll
      for (int q = 0; q < 4; ++q) {
        float v = (acc[i][j][q] + bv) * sc;
        if (do_relu) v = fmaxf(v, 0.0f);
        long idx = (long)(rb + q) * ldc + c;
        if constexpr (OUTBF16) Cb[idx] = (u16)bf16r(v);
        else                   Cf[idx] = v;
      }
    }
  }
}

// ---------------------------------------------------------------------------
DEVI float blockSum(float v, float* sh) {
#pragma unroll
  for (int o = 32; o > 0; o >>= 1) v += __shfl_xor(v, o);
  int w = threadIdx.x >> 6;
  __syncthreads();
  if ((threadIdx.x & 63) == 0) sh[w] = v;
  __syncthreads();
  return (sh[0] + sh[1]) + (sh[2] + sh[3]);
}
DEVI float blockMax(float v, float* sh) {
#pragma unroll
  for (int o = 32; o > 0; o >>= 1) v = fmaxf(v, __shfl_xor(v, o));
  int w = threadIdx.x >> 6;
  __syncthreads();
  if ((threadIdx.x & 63) == 0) sh[w] = v;
  __syncthreads();
  return fmaxf(fmaxf(sh[0], sh[1]), fmaxf(sh[2], sh[3]));
}

// softmax over rows of 1024, in place
__global__ __launch_bounds__(256)
void softmax_rows(float* __restrict__ p) {
  __shared__ float sh[4];
  long row = blockIdx.x;
  float* r = p + row * 1024;
  int t = threadIdx.x;
  f4 v = *(const f4*)(r + t * 4);
  float m = fmaxf(fmaxf(v.x, v.y), fmaxf(v.z, v.w));
  m = blockMax(m, sh);
  f4 e;
  e.x = __expf(v.x - m); e.y = __expf(v.y - m);
  e.z = __expf(v.z - m); e.w = __expf(v.w - m);
  float s = (e.x + e.y) + (e.z + e.w);
  s = blockSum(s, sh);
  float inv = 1.0f / s;
  *(f4*)(r + t * 4) = e * inv;
}

// in = P0 + P1 + resid + bias[c]; LayerNorm(g,be); write fp32 and/or bf16.
template<bool RBF16>
__global__ __launch_bounds__(256)
void ln_combine(const float* __restrict__ P0, const float* __restrict__ P1,
                const void* __restrict__ resid, const float* __restrict__ bias,
                const float* __restrict__ g, const float* __restrict__ be,
                float* __restrict__ outf, u16* __restrict__ outb)
{
  __shared__ float sh[4];
  long row = blockIdx.x;
  int t = threadIdx.x;
  long off = row * 1024 + t * 4;
  f4 v = *(const f4*)(P0 + off);
  v += *(const f4*)(P1 + off);
  if constexpr (RBF16) {
    us4 rp = *(const us4*)((const u16*)resid + off);
    v.x += bf2f(rp.x); v.y += bf2f(rp.y); v.z += bf2f(rp.z); v.w += bf2f(rp.w);
  } else {
    v += *(const f4*)((const float*)resid + off);
  }
  v += *(const f4*)(bias + t * 4);
  float s = (v.x + v.y) + (v.z + v.w);
  s = blockSum(s, sh);
  float mu = s * (1.0f / 1024.0f);
  f4 d = v - mu;
  float s2 = (d.x * d.x + d.y * d.y) + (d.z * d.z + d.w * d.w);
  s2 = blockSum(s2, sh);
  float rs = rsqrtf(s2 * (1.0f / 1024.0f) + 1e-5f);
  f4 gg = *(const f4*)(g + t * 4);
  f4 bb = *(const f4*)(be + t * 4);
  f4 o = d * rs * gg + bb;
  if (outf) *(f4*)(outf + off) = o;
  if (outb) {
    us4 ob;
    ob.x = (u16)bf16r(o.x); ob.y = (u16)bf16r(o.y);
    ob.z = (u16)bf16r(o.z); ob.w = (u16)bf16r(o.w);
    *(us4*)(outb + off) = ob;
  }
}

// fp32 -> bf16 elementwise
__global__ __launch_bounds__(256)
void cvt_bf16(const float* __restrict__ in, u16* __restrict__ out, int n) {
  int i = (blockIdx.x * 256 + threadIdx.x) * 8;
  if (i >= n) return;
  f4 a = *(const f4*)(in + i);
  f4 b = *(const f4*)(in + i + 4);
  *(s8*)(out + i) = cvt8(a, b);
}

// vt[bh][d][s] = qkvb[b, s, 2048 + h*64 + d]   (bf16)
__global__ __launch_bounds__(256)
void transpose_v(const u16* __restrict__ qkv, u16* __restrict__ vt) {
  __shared__ u16 tile[64][72];
  int blk = blockIdx.x, bh = blk >> 4, st = blk & 15;
  int b = bh >> 4, h = bh & 15, s0 = st * 64;
  const u16* gq = qkv + (long)b * 1024 * 3072 + 2048 + (long)h * 64;
  int t = threadIdx.x;
  int sl = t >> 4, dq = (t & 15) * 4;
#pragma unroll
  for (int it = 0; it < 4; ++it) {
    int s = it * 16 + sl;
    us4 v = *(const us4*)(gq + (long)(s0 + s) * 3072 + dq);
    tile[dq + 0][s] = v.x; tile[dq + 1][s] = v.y;
    tile[dq + 2][s] = v.z; tile[dq + 3][s] = v.w;
  }
  __syncthreads();
  u16* o = vt + (long)bh * 65536 + s0;
  int dl = t >> 4, sq = (t & 15) * 4;
#pragma unroll
  for (int it = 0; it < 4; ++it) {
    int d = it * 16 + dl;
    us4 v;
    v.x = tile[d][sq + 0]; v.y = tile[d][sq + 1];
    v.z = tile[d][sq + 2]; v.w = tile[d][sq + 3];
    *(us4*)(o + (long)d * 1024 + sq) = v;
  }
}

// ============================================================================
extern "C" void kernel_launch(void* const* d_in, const int* in_sizes, int n_in,
                              void* d_out, int out_size, void* d_ws, size_t ws_size,
                              hipStream_t stream)
{
  (void)in_sizes; (void)n_in; (void)out_size; (void)ws_size;
  const float* src   = (const float*)d_in[0];
  const float* w_in  = (const float*)d_in[1];
  const float* b_in  = (const float*)d_in[2];
  const float* w_out = (const float*)d_in[3];
  const float* b_out = (const float*)d_in[4];
  const float* w1    = (const float*)d_in[5];
  const float* b1    = (const float*)d_in[6];
  const float* w2    = (const float*)d_in[7];
  const float* b2    = (const float*)d_in[8];
  const float* g1    = (const float*)d_in[9];
  const float* be1   = (const float*)d_in[10];
  const float* g2    = (const float*)d_in[11];
  const float* be2   = (const float*)d_in[12];

  float* out   = (float*)d_out;
  float* attnW = out + (long)4 * 1024 * 1024;

  char* ws = (char*)d_ws;
  u16*   qkvb   = (u16*)(ws);                    // [4096,3072] bf16 (24 MB)
  u16*   vtb    = (u16*)(ws + 25165824);         // [64][64][1024] bf16 (8 MB)
  u16*   h1b    = (u16*)(ws);                    // [4096,4096] bf16 (32 MB, aliases qkvb+vtb)
  u16*   srcb   = (u16*)(ws + 33554432);         // [4096,1024] bf16 (8 MB)
  u16*   w_in_b = (u16*)(ws + 41943040);         // [3072,1024] (6 MB)
  u16*   w_outb = (u16*)(ws + 48234496);         // [1024,1024] (2 MB)
  u16*   w1b    = (u16*)(ws + 50331648);         // [4096,1024] (8 MB)
  u16*   w2b    = (u16*)(ws + 58720256);         // [1024,4096] (8 MB)
  float* P0     = (float*)(ws + 67108864);       // [4096,1024] fp32 (16 MB)
  float* P1     = (float*)(ws + 83886080);       // [4096,1024] fp32 (16 MB)
  u16*   ctxb   = (u16*)(ws + 100663296);        // [4096,1024] bf16 (8 MB)
  u16*   xb     = (u16*)(ws + 109051904);        // [4096,1024] bf16 (8 MB)  [ends 117.4? no: 104+8=112]

  // NOTE: ctxb at 96 MiB = 100663296, xb at 104 MiB = 109051904; total 112 MiB.

  // 0. conversions
  cvt_bf16<<<dim3(2048), 256, 0, stream>>>(src,   srcb,   4194304);
  cvt_bf16<<<dim3(1536), 256, 0, stream>>>(w_in,  w_in_b, 3145728);
  cvt_bf16<<<dim3(512),  256, 0, stream>>>(w_out, w_outb, 1048576);
  cvt_bf16<<<dim3(2048), 256, 0, stream>>>(w1,    w1b,    4194304);
  cvt_bf16<<<dim3(2048), 256, 0, stream>>>(w2,    w2b,    4194304);

  // 1. qkvb = bf16(src @ w_in^T + b_in), q-cols scaled by 0.125
  gemm<128, 128, false, true><<<dim3(24, 32, 1), 256, 0, stream>>>(
      srcb, 1024, 0, 0, w_in_b, 1024, 0, 0, qkvb, 3072, 0, 0, 1,
      b_in, 1024, 1024, 0.125f, 0);

  // 2. vtb = V^T per (b,h)
  transpose_v<<<dim3(1024), 256, 0, stream>>>(qkvb, vtb);

  // 3. scores = q @ k^T -> attnW fp32 (batched 64)
  gemm<128, 128, false, false><<<dim3(8, 8, 64), 256, 0, stream>>>(
      qkvb, 3072, 3145728, 64,
      qkvb + 1024, 3072, 3145728, 64,
      attnW, 1024, 16777216, 1048576, 16,
      nullptr, 64, 0, 1.0f, 0);

  // 4. softmax in place
  softmax_rows<<<dim3(65536), 256, 0, stream>>>(attnW);

  // 5. ctxb = bf16(P @ V)  (A = fp32 attnW, reg-staged)
  gemm<128, 64, true, true><<<dim3(1, 8, 64), 256, 0, stream>>>(
      attnW, 1024, 16777216, 1048576,
      vtb, 1024, 1048576, 65536,
      ctxb, 1024, 1048576, 64, 16,
      nullptr, 1024, 0, 1.0f, 0);

  // 6. out-proj, split-K=2 -> P0,P1
  gemm<128, 128, false, false><<<dim3(8, 32, 2), 256, 0, stream>>>(
      ctxb, 1024, 0, 512, w_outb, 1024, 0, 512,
      P0, 1024, 0, 4194304, 2,
      nullptr, 512, 0, 1.0f, 0);

  // 7. xb = bf16(LN1(P0+P1+src+b_out))
  ln_combine<false><<<dim3(4096), 256, 0, stream>>>(
      P0, P1, src, b_out, g1, be1, nullptr, xb);

  // 8. h1b = bf16(relu(x @ w1^T + b1))
  gemm<128, 128, false, true><<<dim3(32, 32, 1), 256, 0, stream>>>(
      xb, 1024, 0, 0, w1b, 1024, 0, 0, h1b, 4096, 0, 0, 1,
      b1, 1024, 0, 1.0f, 1);

  // 9. FFN2, split-K=2 -> P0,P1
  gemm<128, 128, false, false><<<dim3(8, 32, 2), 256, 0, stream>>>(
      h1b, 4096, 0, 2048, w2b, 4096, 0, 2048,
      P0, 1024, 0, 4194304, 2,
      nullptr, 2048, 0, 1.0f, 0);

  // 10. out = LN2(P0+P1+x+b2)
  ln_combine<true><<<dim3(4096), 256, 0, stream>>>(
      P0, P1, xb, b2, g2, be2, out, nullptr);
}

// Round 3
// 331.686 us; speedup vs baseline: 2.1482x; 1.3144x over previous
//
#include <hip/hip_runtime.h>

// ============================================================================
// EncoderLayerWithAttn — B=4, S=1024, D=1024, H=16, dh=64, DFF=4096
// d_out = [ out fp32 (4M) | attn_weights fp32 (64M) ]
//
// Round 2: fused two-pass flash-style attention (scores+softmax+PV in one
// kernel) writing normalized attn weights fp32 + ctx bf16 directly.
// Removes ~520 MB of HBM traffic vs round 1. cvt kernels merged into one.
//
// Workspace layout (112 MiB):
//   [0,24M):   qkvb bf16 [4096,3072]     -> later h1b bf16 [4096,4096] [0,32M)
//   [24,32M):  vtb  bf16 [64][64][1024]
//   [32,40M):  srcb bf16 [4096,1024]
//   [40,64M):  w_in_b(6) w_out_b(2) w1b(8) w2b(8)
//   [64,96M):  P0,P1 fp32 split-K partials (out-proj, then FFN2)
//   [96,104M): ctxb bf16 [4096,1024]
//   [104,112M): xb bf16 [4096,1024]
// ============================================================================

#define DEVI __device__ __forceinline__

typedef __attribute__((ext_vector_type(4))) float f4;
typedef __attribute__((ext_vector_type(4))) float f32x4;
typedef __attribute__((ext_vector_type(8))) short s8;
typedef __attribute__((ext_vector_type(4))) unsigned short us4;
typedef unsigned short u16;

DEVI short bf16r(float f) {  // fp32 -> bf16 RNE
  unsigned u = __builtin_bit_cast(unsigned, f);
  unsigned r = (u + 0x7fffu + ((u >> 16) & 1u)) >> 16;
  return (short)(unsigned short)r;
}
DEVI float bf2f(u16 h) {
  unsigned u = ((unsigned)h) << 16;
  return __builtin_bit_cast(float, u);
}
DEVI s8 cvt8(f4 a, f4 b) {
  s8 r;
  r[0] = bf16r(a.x); r[1] = bf16r(a.y); r[2] = bf16r(a.z); r[3] = bf16r(a.w);
  r[4] = bf16r(b.x); r[5] = bf16r(b.y); r[6] = bf16r(b.z); r[7] = bf16r(b.w);
  return r;
}

DEVI void gload16(const void* g, void* l) {
  __builtin_amdgcn_global_load_lds(
      (const __attribute__((address_space(1))) unsigned int*)g,
      (__attribute__((address_space(3))) unsigned int*)l, 16, 0, 0);
}

// ---------------------------------------------------------------------------
// Generic NT GEMM (round-1 verified). C[N,M] = A[N,K] @ B[M,K]^T.
template<int BM, int BN, bool A32, bool OUTBF16>
__global__ __launch_bounds__(256)
void gemm(const void* __restrict__ Ap_, long lda, long sAh, long sAl,
          const u16* __restrict__ Bp_, long ldb, long sBh, long sBl,
          void* __restrict__ Cp_, long ldc, long sCh, long sCl, int inner,
          const float* __restrict__ bias, int K,
          int qcols, float qscale, int do_relu)
{
  constexpr int WM = BM / 2, WN = BN / 2, FM = WM / 16, FN = WN / 16;
  constexpr int CA = BM / 32, CB = BN / 32;
  __shared__ __align__(128) short As[BM * 64];
  __shared__ __align__(128) short Bs[BN * 64];

  int z = blockIdx.z, zh = z / inner, zl = z - zh * inner;
  long aoff = (long)zh * sAh + (long)zl * sAl;
  long coff = (long)zh * sCh + (long)zl * sCl;

  int row0 = blockIdx.y * BM, col0 = blockIdx.x * BN;
  int tid = threadIdx.x, lane = tid & 63, w = tid >> 6;
  int wr = w >> 1, wc = w & 1;

  const u16* Bb = Bp_ + (long)zh * sBh + (long)zl * sBl + (long)col0 * ldb;
  const u16* Ab16 = nullptr;
  const float* Ab32 = nullptr;
  if constexpr (A32) Ab32 = (const float*)Ap_ + aoff + (long)row0 * lda;
  else               Ab16 = (const u16*)Ap_ + aoff + (long)row0 * lda;

  f32x4 acc[FM][FN] = {};

  for (int k0 = 0; k0 < K; k0 += 64) {
    if (k0) __syncthreads();
    if constexpr (A32) {
      int r = tid >> 1, half = tid & 1;
      const float* gp = Ab32 + (long)r * lda + k0 + half * 32;
      char* lb = (char*)As + r * 128;
#pragma unroll
      for (int gi = 0; gi < 4; ++gi) {
        f4 v0 = *(const f4*)(gp + gi * 8);
        f4 v1 = *(const f4*)(gp + gi * 8 + 4);
        int g = half * 4 + gi;
        *(s8*)(lb + ((g ^ (r & 7)) * 16)) = cvt8(v0, v1);
      }
    } else {
#pragma unroll
      for (int c = 0; c < CA; ++c) {
        int seg = w * CA + c;
        int r = seg * 8 + (lane >> 3);
        int g = (lane & 7) ^ (r & 7);
        gload16(Ab16 + (long)r * lda + k0 + g * 8, (char*)As + seg * 1024);
      }
    }
#pragma unroll
    for (int c = 0; c < CB; ++c) {
      int seg = w * CB + c;
      int r = seg * 8 + (lane >> 3);
      int g = (lane & 7) ^ (r & 7);
      gload16(Bb + (long)r * ldb + k0 + g * 8, (char*)Bs + seg * 1024);
    }
    __syncthreads();

#pragma unroll
    for (int kk = 0; kk < 2; ++kk) {
      s8 af[FM], bf[FN];
      int lr = lane & 15, kg = kk * 4 + (lane >> 4);
#pragma unroll
      for (int i = 0; i < FM; ++i) {
        int R = wr * WM + i * 16 + lr;
        af[i] = *(const s8*)((char*)As + R * 128 + ((kg ^ (R & 7)) * 16));
      }
#pragma unroll
      for (int j = 0; j < FN; ++j) {
        int R = wc * WN + j * 16 + lr;
        bf[j] = *(const s8*)((char*)Bs + R * 128 + ((kg ^ (R & 7)) * 16));
      }
#pragma unroll
      for (int i = 0; i < FM; ++i)
#pragma unroll
        for (int j = 0; j < FN; ++j)
          acc[i][j] = __builtin_amdgcn_mfma_f32_16x16x32_bf16(af[i], bf[j], acc[i][j], 0, 0, 0);
    }
  }

  float* Cf = (float*)Cp_ + coff;
  u16*   Cb = (u16*)Cp_ + coff;
#pragma unroll
  for (int i = 0; i < FM; ++i) {
#pragma unroll
    for (int j = 0; j < FN; ++j) {
      int rb = row0 + wr * WM + i * 16 + (lane >> 4) * 4;
      int c  = col0 + wc * WN + j * 16 + (lane & 15);
      float bv = bias ? bias[c] : 0.0f;
      float sc = (c < qcols) ? qscale : 1.0f;
#pragma unroll
      for (int q = 0; q < 4; ++q) {
        float v = (acc[i][j][q] + bv) * sc;
        if (do_relu) v = fmaxf(v, 0.0f);
        long idx = (long)(rb + q) * ldc + c;
        if constexpr (OUTBF16) Cb[idx] = (u16)bf16r(v);
        else                   Cf[idx] = v;
      }
    }
  }
}

// ---------------------------------------------------------------------------
// Fused attention: per block = (bh, q-tile of 128 rows). Two-pass exact
// softmax. Writes normalized P fp32 to attnW and ctx bf16.
// LDS: Kt 16K | Vt 16K | Pt 32K (per-wave 8K) = 64 KB. Q staged via Kt.
__global__ __launch_bounds__(256)
void attn_fused(const u16* __restrict__ qkvb, const u16* __restrict__ vtb,
                float* __restrict__ attnW, u16* __restrict__ ctxb)
{
  __shared__ __align__(128) u16 Kt[128 * 64];
  __shared__ __align__(128) u16 Vt[64 * 128];
  __shared__ __align__(128) u16 Pt[4 * 32 * 128];

  int blk = blockIdx.x;
  int bh = blk >> 3, qt = blk & 7;
  int b = bh >> 4, h = bh & 15;
  int tid = threadIdx.x, lane = tid & 63, w = tid >> 6;

  // ---- stage Q tile (128 x 64) into Kt, read per-wave frags ----
  const u16* Qg = qkvb + (long)b * 3145728 + (long)(qt * 128) * 3072 + h * 64;
#pragma unroll
  for (int c = 0; c < 4; ++c) {
    int seg = w * 4 + c;
    int r = seg * 8 + (lane >> 3);
    int g = (lane & 7) ^ (r & 7);
    gload16(Qg + (long)r * 3072 + g * 8, (char*)Kt + seg * 1024);
  }
  __syncthreads();
  s8 aq[2][2];
#pragma unroll
  for (int i = 0; i < 2; ++i)
#pragma unroll
    for (int kk = 0; kk < 2; ++kk) {
      int R = w * 32 + i * 16 + (lane & 15);
      int kg = kk * 4 + (lane >> 4);
      aq[i][kk] = *(const s8*)((char*)Kt + R * 128 + ((kg ^ (R & 7)) * 16));
    }

  const u16* Kbase = qkvb + (long)b * 3145728 + 1024 + h * 64;
  const u16* Vbase = vtb + (long)bh * 65536;

  float m[2][4], l[2][4];
#pragma unroll
  for (int i = 0; i < 2; ++i)
#pragma unroll
    for (int q = 0; q < 4; ++q) { m[i][q] = -1e30f; l[i][q] = 0.0f; }

  // ================= pass 1: running max + denom =================
  for (int kc = 0; kc < 8; ++kc) {
    __syncthreads();
#pragma unroll
    for (int c = 0; c < 4; ++c) {
      int seg = w * 4 + c;
      int r = seg * 8 + (lane >> 3);
      int g = (lane & 7) ^ (r & 7);
      gload16(Kbase + (long)(kc * 128 + r) * 3072 + g * 8, (char*)Kt + seg * 1024);
    }
    __syncthreads();

    f32x4 s[2][8] = {};
#pragma unroll
    for (int kk = 0; kk < 2; ++kk) {
      s8 bk[8];
      int kg = kk * 4 + (lane >> 4);
#pragma unroll
      for (int j = 0; j < 8; ++j) {
        int R = j * 16 + (lane & 15);
        bk[j] = *(const s8*)((char*)Kt + R * 128 + ((kg ^ (R & 7)) * 16));
      }
#pragma unroll
      for (int i = 0; i < 2; ++i)
#pragma unroll
        for (int j = 0; j < 8; ++j)
          s[i][j] = __builtin_amdgcn_mfma_f32_16x16x32_bf16(aq[i][kk], bk[j], s[i][j], 0, 0, 0);
    }

#pragma unroll
    for (int i = 0; i < 2; ++i)
#pragma unroll
      for (int q = 0; q < 4; ++q) {
        float mx = s[i][0][q];
#pragma unroll
        for (int j = 1; j < 8; ++j) mx = fmaxf(mx, s[i][j][q]);
        mx = fmaxf(mx, __shfl_xor(mx, 1));
        mx = fmaxf(mx, __shfl_xor(mx, 2));
        mx = fmaxf(mx, __shfl_xor(mx, 4));
        mx = fmaxf(mx, __shfl_xor(mx, 8));
        float mn = fmaxf(m[i][q], mx);
        float sum = 0.0f;
#pragma unroll
        for (int j = 0; j < 8; ++j) sum += __expf(s[i][j][q] - mn);
        sum += __shfl_xor(sum, 1);
        sum += __shfl_xor(sum, 2);
        sum += __shfl_xor(sum, 4);
        sum += __shfl_xor(sum, 8);
        l[i][q] = l[i][q] * __expf(m[i][q] - mn) + sum;
        m[i][q] = mn;
      }
  }

  float inv[2][4];
#pragma unroll
  for (int i = 0; i < 2; ++i)
#pragma unroll
    for (int q = 0; q < 4; ++q) inv[i][q] = 1.0f / l[i][q];

  // ================= pass 2: P write + PV =================
  f32x4 o_[2][4] = {};
  float* aw = attnW + (long)bh * 1048576 + (long)(qt * 128) * 1024;
  u16* Pw = Pt + w * 4096;  // 32x128 u16 per wave

  for (int kc = 0; kc < 8; ++kc) {
    __syncthreads();
#pragma unroll
    for (int c = 0; c < 4; ++c) {
      int seg = w * 4 + c;
      int r = seg * 8 + (lane >> 3);
      int g = (lane & 7) ^ (r & 7);
      gload16(Kbase + (long)(kc * 128 + r) * 3072 + g * 8, (char*)Kt + seg * 1024);
    }
#pragma unroll
    for (int c = 0; c < 4; ++c) {
      int seg = w * 4 + c;
      int r = seg * 4 + (lane >> 4);          // d row (256 B rows)
      int g = (lane & 15) ^ (r & 7);          // logical granule for linear dest
      gload16(Vbase + (long)r * 1024 + kc * 128 + g * 8, (char*)Vt + seg * 1024);
    }
    __syncthreads();

    f32x4 s[2][8] = {};
#pragma unroll
    for (int kk = 0; kk < 2; ++kk) {
      s8 bk[8];
      int kg = kk * 4 + (lane >> 4);
#pragma unroll
      for (int j = 0; j < 8; ++j) {
        int R = j * 16 + (lane & 15);
        bk[j] = *(const s8*)((char*)Kt + R * 128 + ((kg ^ (R & 7)) * 16));
      }
#pragma unroll
      for (int i = 0; i < 2; ++i)
#pragma unroll
        for (int j = 0; j < 8; ++j)
          s[i][j] = __builtin_amdgcn_mfma_f32_16x16x32_bf16(aq[i][kk], bk[j], s[i][j], 0, 0, 0);
    }

    // P = exp(s-m)*inv: write fp32 to attnW, bf16 to swizzled per-wave LDS
#pragma unroll
    for (int i = 0; i < 2; ++i)
#pragma unroll
      for (int j = 0; j < 8; ++j)
#pragma unroll
        for (int q = 0; q < 4; ++q) {
          float p = __expf(s[i][j][q] - m[i][q]) * inv[i][q];
          int R = i * 16 + (lane >> 4) * 4 + q;   // row within wave's 32
          int C = j * 16 + (lane & 15);           // key within chunk
          aw[(long)(w * 32 + R) * 1024 + kc * 128 + C] = p;
          *(u16*)((char*)Pw + R * 256 + (((C >> 3) ^ (R & 7)) * 16) + (C & 7) * 2)
              = (u16)bf16r(p);
        }

    // PV: contraction over 128 keys (4 kk-steps)
#pragma unroll
    for (int kks = 0; kks < 4; ++kks) {
      int kg = kks * 4 + (lane >> 4);
      s8 pa[2], bv[4];
#pragma unroll
      for (int i = 0; i < 2; ++i) {
        int R = i * 16 + (lane & 15);
        pa[i] = *(const s8*)((char*)Pw + R * 256 + ((kg ^ (R & 7)) * 16));
      }
#pragma unroll
      for (int j = 0; j < 4; ++j) {
        int R = j * 16 + (lane & 15);
        bv[j] = *(const s8*)((char*)Vt + R * 256 + ((kg ^ (R & 7)) * 16));
      }
#pragma unroll
      for (int i = 0; i < 2; ++i)
#pragma unroll
        for (int j = 0; j < 4; ++j)
          o_[i][j] = __builtin_amdgcn_mfma_f32_16x16x32_bf16(pa[i], bv[j], o_[i][j], 0, 0, 0);
    }
  }

  // ---- write ctx bf16 [4096,1024], col offset h*64 ----
#pragma unroll
  for (int i = 0; i < 2; ++i)
#pragma unroll
    for (int j = 0; j < 4; ++j)
#pragma unroll
      for (int q = 0; q < 4; ++q) {
        int R = w * 32 + i * 16 + (lane >> 4) * 4 + q;
        int col = h * 64 + j * 16 + (lane & 15);
        ctxb[(long)(b * 1024 + qt * 128 + R) * 1024 + col] = (u16)bf16r(o_[i][j][q]);
      }
}

// ---------------------------------------------------------------------------
DEVI float blockSum(float v, float* sh) {
#pragma unroll
  for (int o = 32; o > 0; o >>= 1) v += __shfl_xor(v, o);
  int w = threadIdx.x >> 6;
  __syncthreads();
  if ((threadIdx.x & 63) == 0) sh[w] = v;
  __syncthreads();
  return (sh[0] + sh[1]) + (sh[2] + sh[3]);
}

// in = P0 + P1 + resid + bias[c]; LayerNorm(g,be); write fp32 and/or bf16.
template<bool RBF16>
__global__ __launch_bounds__(256)
void ln_combine(const float* __restrict__ P0, const float* __restrict__ P1,
                const void* __restrict__ resid, const float* __restrict__ bias,
                const float* __restrict__ g, const float* __restrict__ be,
                float* __restrict__ outf, u16* __restrict__ outb)
{
  __shared__ float sh[4];
  long row = blockIdx.x;
  int t = threadIdx.x;
  long off = row * 1024 + t * 4;
  f4 v = *(const f4*)(P0 + off);
  v += *(const f4*)(P1 + off);
  if constexpr (RBF16) {
    us4 rp = *(const us4*)((const u16*)resid + off);
    v.x += bf2f(rp.x); v.y += bf2f(rp.y); v.z += bf2f(rp.z); v.w += bf2f(rp.w);
  } else {
    v += *(const f4*)((const float*)resid + off);
  }
  v += *(const f4*)(bias + t * 4);
  float s = (v.x + v.y) + (v.z + v.w);
  s = blockSum(s, sh);
  float mu = s * (1.0f / 1024.0f);
  f4 d = v - mu;
  float s2 = (d.x * d.x + d.y * d.y) + (d.z * d.z + d.w * d.w);
  s2 = blockSum(s2, sh);
  float rs = rsqrtf(s2 * (1.0f / 1024.0f) + 1e-5f);
  f4 gg = *(const f4*)(g + t * 4);
  f4 bb = *(const f4*)(be + t * 4);
  f4 o = d * rs * gg + bb;
  if (outf) *(f4*)(outf + off) = o;
  if (outb) {
    us4 ob;
    ob.x = (u16)bf16r(o.x); ob.y = (u16)bf16r(o.y);
    ob.z = (u16)bf16r(o.z); ob.w = (u16)bf16r(o.w);
    *(us4*)(outb + off) = ob;
  }
}

// all five fp32->bf16 conversions in one launch (8192 blocks x 2048 elems)
__global__ __launch_bounds__(256)
void cvt_all(const float* __restrict__ s0, const float* __restrict__ s1,
             const float* __restrict__ s2, const float* __restrict__ s3,
             const float* __restrict__ s4,
             u16* __restrict__ d0, u16* __restrict__ d1, u16* __restrict__ d2,
             u16* __restrict__ d3, u16* __restrict__ d4)
{
  int bi = blockIdx.x;
  const float* s; u16* d; int base;
  if      (bi < 2048) { s = s0; d = d0; base = bi; }
  else if (bi < 3584) { s = s1; d = d1; base = bi - 2048; }
  else if (bi < 4096) { s = s2; d = d2; base = bi - 3584; }
  else if (bi < 6144) { s = s3; d = d3; base = bi - 4096; }
  else                { s = s4; d = d4; base = bi - 6144; }
  long i = ((long)base * 256 + threadIdx.x) * 8;
  f4 a = *(const f4*)(s + i);
  f4 b = *(const f4*)(s + i + 4);
  *(s8*)(d + i) = cvt8(a, b);
}

// vt[bh][d][s] = qkvb[b, s, 2048 + h*64 + d]   (bf16)
__global__ __launch_bounds__(256)
void transpose_v(const u16* __restrict__ qkv, u16* __restrict__ vt) {
  __shared__ u16 tile[64][72];
  int blk = blockIdx.x, bh = blk >> 4, st = blk & 15;
  int b = bh >> 4, h = bh & 15, s0 = st * 64;
  const u16* gq = qkv + (long)b * 1024 * 3072 + 2048 + (long)h * 64;
  int t = threadIdx.x;
  int sl = t >> 4, dq = (t & 15) * 4;
#pragma unroll
  for (int it = 0; it < 4; ++it) {
    int s = it * 16 + sl;
    us4 v = *(const us4*)(gq + (long)(s0 + s) * 3072 + dq);
    tile[dq + 0][s] = v.x; tile[dq + 1][s] = v.y;
    tile[dq + 2][s] = v.z; tile[dq + 3][s] = v.w;
  }
  __syncthreads();
  u16* o = vt + (long)bh * 65536 + s0;
  int dl = t >> 4, sq = (t & 15) * 4;
#pragma unroll
  for (int it = 0; it < 4; ++it) {
    int d = it * 16 + dl;
    us4 v;
    v.x = tile[d][sq + 0]; v.y = tile[d][sq + 1];
    v.z = tile[d][sq + 2]; v.w = tile[d][sq + 3];
    *(us4*)(o + (long)d * 1024 + sq) = v;
  }
}

// ============================================================================
extern "C" void kernel_launch(void* const* d_in, const int* in_sizes, int n_in,
                              void* d_out, int out_size, void* d_ws, size_t ws_size,
                              hipStream_t stream)
{
  (void)in_sizes; (void)n_in; (void)out_size; (void)ws_size;
  const float* src   = (const float*)d_in[0];
  const float* w_in  = (const float*)d_in[1];
  const float* b_in  = (const float*)d_in[2];
  const float* w_out = (const float*)d_in[3];
  const float* b_out = (const float*)d_in[4];
  const float* w1    = (const float*)d_in[5];
  const float* b1    = (const float*)d_in[6];
  const float* w2    = (const float*)d_in[7];
  const float* b2    = (const float*)d_in[8];
  const float* g1    = (const float*)d_in[9];
  const float* be1   = (const float*)d_in[10];
  const float* g2    = (const float*)d_in[11];
  const float* be2   = (const float*)d_in[12];

  float* out   = (float*)d_out;
  float* attnW = out + (long)4 * 1024 * 1024;

  char* ws = (char*)d_ws;
  u16*   qkvb   = (u16*)(ws);                    // [4096,3072] bf16 (24 MB)
  u16*   vtb    = (u16*)(ws + 25165824);         // [64][64][1024] bf16 (8 MB)
  u16*   h1b    = (u16*)(ws);                    // [4096,4096] bf16 (32 MB)
  u16*   srcb   = (u16*)(ws + 33554432);         // [4096,1024] bf16 (8 MB)
  u16*   w_in_b = (u16*)(ws + 41943040);         // [3072,1024] (6 MB)
  u16*   w_outb = (u16*)(ws + 48234496);         // [1024,1024] (2 MB)
  u16*   w1b    = (u16*)(ws + 50331648);         // [4096,1024] (8 MB)
  u16*   w2b    = (u16*)(ws + 58720256);         // [1024,4096] (8 MB)
  float* P0     = (float*)(ws + 67108864);       // [4096,1024] fp32 (16 MB)
  float* P1     = (float*)(ws + 83886080);       // [4096,1024] fp32 (16 MB)
  u16*   ctxb   = (u16*)(ws + 100663296);        // [4096,1024] bf16 (8 MB)
  u16*   xb     = (u16*)(ws + 109051904);        // [4096,1024] bf16 (8 MB)

  // 0. conversions (merged)
  cvt_all<<<dim3(8192), 256, 0, stream>>>(src, w_in, w_out, w1, w2,
                                          srcb, w_in_b, w_outb, w1b, w2b);

  // 1. qkvb = bf16(src @ w_in^T + b_in), q-cols scaled by 0.125
  gemm<128, 128, false, true><<<dim3(24, 32, 1), 256, 0, stream>>>(
      srcb, 1024, 0, 0, w_in_b, 1024, 0, 0, qkvb, 3072, 0, 0, 1,
      b_in, 1024, 1024, 0.125f, 0);

  // 2. vtb = V^T per (b,h)
  transpose_v<<<dim3(1024), 256, 0, stream>>>(qkvb, vtb);

  // 3. fused attention: attnW fp32 + ctxb bf16
  attn_fused<<<dim3(512), 256, 0, stream>>>(qkvb, vtb, attnW, ctxb);

  // 4. out-proj, split-K=2 -> P0,P1
  gemm<128, 128, false, false><<<dim3(8, 32, 2), 256, 0, stream>>>(
      ctxb, 1024, 0, 512, w_outb, 1024, 0, 512,
      P0, 1024, 0, 4194304, 2,
      nullptr, 512, 0, 1.0f, 0);

  // 5. xb = bf16(LN1(P0+P1+src+b_out))
  ln_combine<false><<<dim3(4096), 256, 0, stream>>>(
      P0, P1, src, b_out, g1, be1, nullptr, xb);

  // 6. h1b = bf16(relu(x @ w1^T + b1))
  gemm<128, 128, false, true><<<dim3(32, 32, 1), 256, 0, stream>>>(
      xb, 1024, 0, 0, w1b, 1024, 0, 0, h1b, 4096, 0, 0, 1,
      b1, 1024, 0, 1.0f, 1);

  // 7. FFN2, split-K=2 -> P0,P1
  gemm<128, 128, false, false><<<dim3(8, 32, 2), 256, 0, stream>>>(
      h1b, 4096, 0, 2048, w2b, 4096, 0, 2048,
      P0, 1024, 0, 4194304, 2,
      nullptr, 2048, 0, 1.0f, 0);

  // 8. out = LN2(P0+P1+x+b2)
  ln_combine<true><<<dim3(4096), 256, 0, stream>>>(
      P0, P1, xb, b2, g2, be2, out, nullptr);
}

// Round 5
// 329.944 us; speedup vs baseline: 2.1596x; 1.0053x over previous
//
#include <hip/hip_runtime.h>

// ============================================================================
// EncoderLayerWithAttn — B=4, S=1024, D=1024, H=16, dh=64, DFF=4096
// d_out = [ out fp32 (4M) | attn_weights fp32 (64M) ]
//
// Round 4: fix round-3 race in gemm256. Invariant (m201): every wave does
// vmcnt(N) BEFORE a shared barrier; ds_reads only after that barrier.
// Round 3 had VM4();ds_read with no barrier between -> cross-wave race on
// LDS tiles (vmcnt is per-wave). Three edits: prologue VM4+BAR, phase-odd
// VM4 removed, phase-even VM4 moved before the closing BAR.
//
// Workspace (112 MiB):
//   [0,24M)  qkvb bf16         -> Q0[0,16) Q1[16,32) -> h1b bf16 [0,32M)
//   [24,32M) vtb bf16
//   [32,40M) srcb bf16         -> R0 [32,48M)
//   [40,48M) ctxb bf16
//   [48,56M) xb bf16 (alive to end)
//   [56,62M) w_in_b  [62,64M) w_outb  [64,72M) w1b   -> R1 [56,72M)
//   [72,80M) w2b
//   [80,96M) Q2/R2   [96,112M) Q3/R3
// ============================================================================

#define DEVI __device__ __forceinline__

typedef __attribute__((ext_vector_type(4))) float f4;
typedef __attribute__((ext_vector_type(4))) float f32x4;
typedef __attribute__((ext_vector_type(8))) short s8;
typedef __attribute__((ext_vector_type(4))) unsigned short us4;
typedef unsigned short u16;

DEVI short bf16r(float f) {  // fp32 -> bf16 RNE
  unsigned u = __builtin_bit_cast(unsigned, f);
  unsigned r = (u + 0x7fffu + ((u >> 16) & 1u)) >> 16;
  return (short)(unsigned short)r;
}
DEVI float bf2f(u16 h) {
  unsigned u = ((unsigned)h) << 16;
  return __builtin_bit_cast(float, u);
}
DEVI s8 cvt8(f4 a, f4 b) {
  s8 r;
  r[0] = bf16r(a.x); r[1] = bf16r(a.y); r[2] = bf16r(a.z); r[3] = bf16r(a.w);
  r[4] = bf16r(b.x); r[5] = bf16r(b.y); r[6] = bf16r(b.z); r[7] = bf16r(b.w);
  return r;
}

DEVI void gload16(const void* g, void* l) {
  __builtin_amdgcn_global_load_lds(
      (const __attribute__((address_space(1))) unsigned int*)g,
      (__attribute__((address_space(3))) unsigned int*)l, 16, 0, 0);
}

#define BAR()   __builtin_amdgcn_s_barrier()
#define LGKM0() do { asm volatile("s_waitcnt lgkmcnt(0)" ::: "memory"); \
                     __builtin_amdgcn_sched_barrier(0); } while (0)
#define VM4()   do { asm volatile("s_waitcnt vmcnt(4)" ::: "memory"); \
                     __builtin_amdgcn_sched_barrier(0); } while (0)

// ---------------------------------------------------------------------------
// C[rows, cols] = A[rows,K]@B[cols,K]^T. 256x256 tile, 512 thr (8 waves 2Mx4N),
// BK=32, ring-3 LDS. Per K-tile: 2 phases x 16 MFMA. Stage of tile t+2 issued
// during tile t; VM4 -> BAR published once per tile (end of phase even).
// LDS rows 64B, granule swizzle phys = g ^ ((row>>1)&3) on both sides.
template<bool OUTBF16>
__global__ __launch_bounds__(512, 2)
void gemm256(const u16* __restrict__ A, long lda, long sA,
             const u16* __restrict__ B, long ldb, long sB,
             void* __restrict__ Cp, long ldc,
             long c0, long c1, long c2, long c3,
             const float* __restrict__ bias, int K,
             int qcols, float qscale, int do_relu)
{
  __shared__ __align__(128) char LDS[98304];  // A: 3x16KB @0, B: 3x16KB @48K

  const int tid = threadIdx.x, lane = tid & 63, w = tid >> 6;
  const int wr = w >> 2, wc = w & 3;
  const int z = blockIdx.z;
  const int row0 = blockIdx.y * 256, col0 = blockIdx.x * 256;

  const u16* Ag = A + (long)z * sA + (long)row0 * lda;
  const u16* Bg = B + (long)z * sB + (long)col0 * ldb;
  long coff = (z == 0) ? c0 : (z == 1) ? c1 : (z == 2) ? c2 : c3;

  const int NT = K >> 5;

  // stage source lane mapping: row r = w*16 + (lane>>2), granule slot lane&3
  const int sr = (w << 4) + (lane >> 2);
  const int gsrc = (lane & 3) ^ ((sr >> 1) & 3);

  auto stageA = [&](int kt, int slot) {
#pragma unroll
    for (int h = 0; h < 2; ++h)
      gload16(Ag + (long)(h * 128 + sr) * lda + kt * 32 + gsrc * 8,
              LDS + slot * 16384 + h * 8192 + (w << 10));
  };
  auto stageB = [&](int kt, int slot) {
#pragma unroll
    for (int h = 0; h < 2; ++h)
      gload16(Bg + (long)(h * 128 + sr) * ldb + kt * 32 + gsrc * 8,
              LDS + 49152 + slot * 16384 + h * 8192 + (w << 10));
  };

  const int kg = lane >> 4, lr = lane & 15;
  auto rdA = [&](int buf, int fig, s8* aF) {
#pragma unroll
    for (int i = 0; i < 4; ++i) {
      int R = wr * 128 + (fig * 4 + i) * 16 + lr;
      aF[i] = *(const s8*)(LDS + buf * 16384 + R * 64 + ((kg ^ ((R >> 1) & 3)) << 4));
    }
  };
  auto rdB = [&](int buf, s8* bF) {
#pragma unroll
    for (int j = 0; j < 4; ++j) {
      int R = wc * 64 + j * 16 + lr;
      bF[j] = *(const s8*)(LDS + 49152 + buf * 16384 + R * 64 + ((kg ^ ((R >> 1) & 3)) << 4));
    }
  };

  f32x4 acc[8][4] = {};

  // prologue: stage tiles 0,1; publish tile 0 (VM4 -> BAR) before first read
  stageA(0, 0); stageB(0, 0);
  stageA(1, 1); stageB(1, 1);
  VM4();
  BAR();

  int buf = 0;
  for (int t = 0; t < NT; ++t) {
    int nbuf = buf + 2; if (nbuf >= 3) nbuf -= 3;
    int tc = (t + 2 < NT) ? t + 2 : NT - 1;
    s8 aF[4], bF[4], aG[4];

    // ---- phase odd: read B + A(fig0), stage A(t+2), MFMA fig0 ----
    rdB(buf, bF);
    rdA(buf, 0, aF);
    stageA(tc, nbuf);
    BAR();
    LGKM0();
    __builtin_amdgcn_s_setprio(1);
#pragma unroll
    for (int i = 0; i < 4; ++i)
#pragma unroll
      for (int j = 0; j < 4; ++j)
        acc[i][j] = __builtin_amdgcn_mfma_f32_16x16x32_bf16(aF[i], bF[j], acc[i][j], 0, 0, 0);
    __builtin_amdgcn_s_setprio(0);
    BAR();

    // ---- phase even: read A(fig1), stage B(t+2), MFMA fig1 ----
    rdA(buf, 1, aG);
    stageB(tc, nbuf);
    BAR();
    LGKM0();
    __builtin_amdgcn_s_setprio(1);
#pragma unroll
    for (int i = 0; i < 4; ++i)
#pragma unroll
      for (int j = 0; j < 4; ++j)
        acc[4 + i][j] = __builtin_amdgcn_mfma_f32_16x16x32_bf16(aG[i], bF[j], acc[4 + i][j], 0, 0, 0);
    __builtin_amdgcn_s_setprio(0);
    VM4();   // certify tile t+1's loads retired (this wave) ...
    BAR();   // ... then publish to all waves; t+1 reads are now safe
    buf = (buf == 2) ? 0 : buf + 1;
  }
  asm volatile("s_waitcnt vmcnt(0)" ::: "memory");

  // ---- epilogue: C/D layout col=lane&15, row=(lane>>4)*4+q ----
  float* Cf = (float*)Cp + coff;
  u16*   Cb = (u16*)Cp + coff;
#pragma unroll
  for (int fi = 0; fi < 8; ++fi) {
#pragma unroll
    for (int fj = 0; fj < 4; ++fj) {
      int rb = row0 + wr * 128 + fi * 16 + (lane >> 4) * 4;
      int c  = col0 + wc * 64 + fj * 16 + lr;
      float bv = bias ? bias[c] : 0.0f;
      float sc = (c < qcols) ? qscale : 1.0f;
#pragma unroll
      for (int q = 0; q < 4; ++q) {
        float v = (acc[fi][fj][q] + bv) * sc;
        if (do_relu) v = fmaxf(v, 0.0f);
        long idx = (long)(rb + q) * ldc + c;
        if constexpr (OUTBF16) Cb[idx] = (u16)bf16r(v);
        else                   Cf[idx] = v;
      }
    }
  }
}

// ---------------------------------------------------------------------------
// Fused attention (round-2 verified, unchanged).
__global__ __launch_bounds__(256)
void attn_fused(const u16* __restrict__ qkvb, const u16* __restrict__ vtb,
                float* __restrict__ attnW, u16* __restrict__ ctxb)
{
  __shared__ __align__(128) u16 Kt[128 * 64];
  __shared__ __align__(128) u16 Vt[64 * 128];
  __shared__ __align__(128) u16 Pt[4 * 32 * 128];

  int blk = blockIdx.x;
  int bh = blk >> 3, qt = blk & 7;
  int b = bh >> 4, h = bh & 15;
  int tid = threadIdx.x, lane = tid & 63, w = tid >> 6;

  const u16* Qg = qkvb + (long)b * 3145728 + (long)(qt * 128) * 3072 + h * 64;
#pragma unroll
  for (int c = 0; c < 4; ++c) {
    int seg = w * 4 + c;
    int r = seg * 8 + (lane >> 3);
    int g = (lane & 7) ^ (r & 7);
    gload16(Qg + (long)r * 3072 + g * 8, (char*)Kt + seg * 1024);
  }
  __syncthreads();
  s8 aq[2][2];
#pragma unroll
  for (int i = 0; i < 2; ++i)
#pragma unroll
    for (int kk = 0; kk < 2; ++kk) {
      int R = w * 32 + i * 16 + (lane & 15);
      int kgq = kk * 4 + (lane >> 4);
      aq[i][kk] = *(const s8*)((char*)Kt + R * 128 + ((kgq ^ (R & 7)) * 16));
    }

  const u16* Kbase = qkvb + (long)b * 3145728 + 1024 + h * 64;
  const u16* Vbase = vtb + (long)bh * 65536;

  float m[2][4], l[2][4];
#pragma unroll
  for (int i = 0; i < 2; ++i)
#pragma unroll
    for (int q = 0; q < 4; ++q) { m[i][q] = -1e30f; l[i][q] = 0.0f; }

  // ===== pass 1: running max + denom =====
  for (int kc = 0; kc < 8; ++kc) {
    __syncthreads();
#pragma unroll
    for (int c = 0; c < 4; ++c) {
      int seg = w * 4 + c;
      int r = seg * 8 + (lane >> 3);
      int g = (lane & 7) ^ (r & 7);
      gload16(Kbase + (long)(kc * 128 + r) * 3072 + g * 8, (char*)Kt + seg * 1024);
    }
    __syncthreads();

    f32x4 s[2][8] = {};
#pragma unroll
    for (int kk = 0; kk < 2; ++kk) {
      s8 bk[8];
      int kgq = kk * 4 + (lane >> 4);
#pragma unroll
      for (int j = 0; j < 8; ++j) {
        int R = j * 16 + (lane & 15);
        bk[j] = *(const s8*)((char*)Kt + R * 128 + ((kgq ^ (R & 7)) * 16));
      }
#pragma unroll
      for (int i = 0; i < 2; ++i)
#pragma unroll
        for (int j = 0; j < 8; ++j)
          s[i][j] = __builtin_amdgcn_mfma_f32_16x16x32_bf16(aq[i][kk], bk[j], s[i][j], 0, 0, 0);
    }

#pragma unroll
    for (int i = 0; i < 2; ++i)
#pragma unroll
      for (int q = 0; q < 4; ++q) {
        float mx = s[i][0][q];
#pragma unroll
        for (int j = 1; j < 8; ++j) mx = fmaxf(mx, s[i][j][q]);
        mx = fmaxf(mx, __shfl_xor(mx, 1));
        mx = fmaxf(mx, __shfl_xor(mx, 2));
        mx = fmaxf(mx, __shfl_xor(mx, 4));
        mx = fmaxf(mx, __shfl_xor(mx, 8));
        float mn = fmaxf(m[i][q], mx);
        float sum = 0.0f;
#pragma unroll
        for (int j = 0; j < 8; ++j) sum += __expf(s[i][j][q] - mn);
        sum += __shfl_xor(sum, 1);
        sum += __shfl_xor(sum, 2);
        sum += __shfl_xor(sum, 4);
        sum += __shfl_xor(sum, 8);
        l[i][q] = l[i][q] * __expf(m[i][q] - mn) + sum;
        m[i][q] = mn;
      }
  }

  float inv[2][4];
#pragma unroll
  for (int i = 0; i < 2; ++i)
#pragma unroll
    for (int q = 0; q < 4; ++q) inv[i][q] = 1.0f / l[i][q];

  // ===== pass 2: P write + PV =====
  f32x4 o_[2][4] = {};
  float* aw = attnW + (long)bh * 1048576 + (long)(qt * 128) * 1024;
  u16* Pw = Pt + w * 4096;

  for (int kc = 0; kc < 8; ++kc) {
    __syncthreads();
#pragma unroll
    for (int c = 0; c < 4; ++c) {
      int seg = w * 4 + c;
      int r = seg * 8 + (lane >> 3);
      int g = (lane & 7) ^ (r & 7);
      gload16(Kbase + (long)(kc * 128 + r) * 3072 + g * 8, (char*)Kt + seg * 1024);
    }
#pragma unroll
    for (int c = 0; c < 4; ++c) {
      int seg = w * 4 + c;
      int r = seg * 4 + (lane >> 4);
      int g = (lane & 15) ^ (r & 7);
      gload16(Vbase + (long)r * 1024 + kc * 128 + g * 8, (char*)Vt + seg * 1024);
    }
    __syncthreads();

    f32x4 s[2][8] = {};
#pragma unroll
    for (int kk = 0; kk < 2; ++kk) {
      s8 bk[8];
      int kgq = kk * 4 + (lane >> 4);
#pragma unroll
      for (int j = 0; j < 8; ++j) {
        int R = j * 16 + (lane & 15);
        bk[j] = *(const s8*)((char*)Kt + R * 128 + ((kgq ^ (R & 7)) * 16));
      }
#pragma unroll
      for (int i = 0; i < 2; ++i)
#pragma unroll
        for (int j = 0; j < 8; ++j)
          s[i][j] = __builtin_amdgcn_mfma_f32_16x16x32_bf16(aq[i][kk], bk[j], s[i][j], 0, 0, 0);
    }

#pragma unroll
    for (int i = 0; i < 2; ++i)
#pragma unroll
      for (int j = 0; j < 8; ++j)
#pragma unroll
        for (int q = 0; q < 4; ++q) {
          float p = __expf(s[i][j][q] - m[i][q]) * inv[i][q];
          int R = i * 16 + (lane >> 4) * 4 + q;
          int C = j * 16 + (lane & 15);
          aw[(long)(w * 32 + R) * 1024 + kc * 128 + C] = p;
          *(u16*)((char*)Pw + R * 256 + (((C >> 3) ^ (R & 7)) * 16) + (C & 7) * 2)
              = (u16)bf16r(p);
        }

#pragma unroll
    for (int kks = 0; kks < 4; ++kks) {
      int kgq = kks * 4 + (lane >> 4);
      s8 pa[2], bv[4];
#pragma unroll
      for (int i = 0; i < 2; ++i) {
        int R = i * 16 + (lane & 15);
        pa[i] = *(const s8*)((char*)Pw + R * 256 + ((kgq ^ (R & 7)) * 16));
      }
#pragma unroll
      for (int j = 0; j < 4; ++j) {
        int R = j * 16 + (lane & 15);
        bv[j] = *(const s8*)((char*)Vt + R * 256 + ((kgq ^ (R & 7)) * 16));
      }
#pragma unroll
      for (int i = 0; i < 2; ++i)
#pragma unroll
        for (int j = 0; j < 4; ++j)
          o_[i][j] = __builtin_amdgcn_mfma_f32_16x16x32_bf16(pa[i], bv[j], o_[i][j], 0, 0, 0);
    }
  }

#pragma unroll
  for (int i = 0; i < 2; ++i)
#pragma unroll
    for (int j = 0; j < 4; ++j)
#pragma unroll
      for (int q = 0; q < 4; ++q) {
        int R = w * 32 + i * 16 + (lane >> 4) * 4 + q;
        int col = h * 64 + j * 16 + (lane & 15);
        ctxb[(long)(b * 1024 + qt * 128 + R) * 1024 + col] = (u16)bf16r(o_[i][j][q]);
      }
}

// ---------------------------------------------------------------------------
DEVI float blockSum(float v, float* sh) {
#pragma unroll
  for (int o = 32; o > 0; o >>= 1) v += __shfl_xor(v, o);
  int w = threadIdx.x >> 6;
  __syncthreads();
  if ((threadIdx.x & 63) == 0) sh[w] = v;
  __syncthreads();
  return (sh[0] + sh[1]) + (sh[2] + sh[3]);
}

// in = P0+P1+P2+P3 + resid + bias[c]; LayerNorm(g,be); write fp32 and/or bf16
template<bool RBF16>
__global__ __launch_bounds__(256)
void ln_combine4(const float* __restrict__ P0, const float* __restrict__ P1,
                 const float* __restrict__ P2, const float* __restrict__ P3,
                 const void* __restrict__ resid, const float* __restrict__ bias,
                 const float* __restrict__ g, const float* __restrict__ be,
                 float* __restrict__ outf, u16* __restrict__ outb)
{
  __shared__ float sh[4];
  long row = blockIdx.x;
  int t = threadIdx.x;
  long off = row * 1024 + t * 4;
  f4 v = *(const f4*)(P0 + off);
  v += *(const f4*)(P1 + off);
  v += *(const f4*)(P2 + off);
  v += *(const f4*)(P3 + off);
  if constexpr (RBF16) {
    us4 rp = *(const us4*)((const u16*)resid + off);
    v.x += bf2f(rp.x); v.y += bf2f(rp.y); v.z += bf2f(rp.z); v.w += bf2f(rp.w);
  } else {
    v += *(const f4*)((const float*)resid + off);
  }
  v += *(const f4*)(bias + t * 4);
  float s = (v.x + v.y) + (v.z + v.w);
  s = blockSum(s, sh);
  float mu = s * (1.0f / 1024.0f);
  f4 d = v - mu;
  float s2 = (d.x * d.x + d.y * d.y) + (d.z * d.z + d.w * d.w);
  s2 = blockSum(s2, sh);
  float rs = rsqrtf(s2 * (1.0f / 1024.0f) + 1e-5f);
  f4 gg = *(const f4*)(g + t * 4);
  f4 bb = *(const f4*)(be + t * 4);
  f4 o = d * rs * gg + bb;
  if (outf) *(f4*)(outf + off) = o;
  if (outb) {
    us4 ob;
    ob.x = (u16)bf16r(o.x); ob.y = (u16)bf16r(o.y);
    ob.z = (u16)bf16r(o.z); ob.w = (u16)bf16r(o.w);
    *(us4*)(outb + off) = ob;
  }
}

// all five fp32->bf16 conversions in one launch
__global__ __launch_bounds__(256)
void cvt_all(const float* __restrict__ s0, const float* __restrict__ s1,
             const float* __restrict__ s2, const float* __restrict__ s3,
             const float* __restrict__ s4,
             u16* __restrict__ d0, u16* __restrict__ d1, u16* __restrict__ d2,
             u16* __restrict__ d3, u16* __restrict__ d4)
{
  int bi = blockIdx.x;
  const float* s; u16* d; int base;
  if      (bi < 2048) { s = s0; d = d0; base = bi; }
  else if (bi < 3584) { s = s1; d = d1; base = bi - 2048; }
  else if (bi < 4096) { s = s2; d = d2; base = bi - 3584; }
  else if (bi < 6144) { s = s3; d = d3; base = bi - 4096; }
  else                { s = s4; d = d4; base = bi - 6144; }
  long i = ((long)base * 256 + threadIdx.x) * 8;
  f4 a = *(const f4*)(s + i);
  f4 b = *(const f4*)(s + i + 4);
  *(s8*)(d + i) = cvt8(a, b);
}

// vt[bh][d][s] = qkvb[b, s, 2048 + h*64 + d]   (bf16)
__global__ __launch_bounds__(256)
void transpose_v(const u16* __restrict__ qkv, u16* __restrict__ vt) {
  __shared__ u16 tile[64][72];
  int blk = blockIdx.x, bh = blk >> 4, st = blk & 15;
  int b = bh >> 4, h = bh & 15, s0 = st * 64;
  const u16* gq = qkv + (long)b * 1024 * 3072 + 2048 + (long)h * 64;
  int t = threadIdx.x;
  int sl = t >> 4, dq = (t & 15) * 4;
#pragma unroll
  for (int it = 0; it < 4; ++it) {
    int s = it * 16 + sl;
    us4 v = *(const us4*)(gq + (long)(s0 + s) * 3072 + dq);
    tile[dq + 0][s] = v.x; tile[dq + 1][s] = v.y;
    tile[dq + 2][s] = v.z; tile[dq + 3][s] = v.w;
  }
  __syncthreads();
  u16* o = vt + (long)bh * 65536 + s0;
  int dl = t >> 4, sq = (t & 15) * 4;
#pragma unroll
  for (int it = 0; it < 4; ++it) {
    int d = it * 16 + dl;
    us4 v;
    v.x = tile[d][sq + 0]; v.y = tile[d][sq + 1];
    v.z = tile[d][sq + 2]; v.w = tile[d][sq + 3];
    *(us4*)(o + (long)d * 1024 + sq) = v;
  }
}

// ============================================================================
extern "C" void kernel_launch(void* const* d_in, const int* in_sizes, int n_in,
                              void* d_out, int out_size, void* d_ws, size_t ws_size,
                              hipStream_t stream)
{
  (void)in_sizes; (void)n_in; (void)out_size; (void)ws_size;
  const float* src   = (const float*)d_in[0];
  const float* w_in  = (const float*)d_in[1];
  const float* b_in  = (const float*)d_in[2];
  const float* w_out = (const float*)d_in[3];
  const float* b_out = (const float*)d_in[4];
  const float* w1    = (const float*)d_in[5];
  const float* b1    = (const float*)d_in[6];
  const float* w2    = (const float*)d_in[7];
  const float* b2    = (const float*)d_in[8];
  const float* g1    = (const float*)d_in[9];
  const float* be1   = (const float*)d_in[10];
  const float* g2    = (const float*)d_in[11];
  const float* be2   = (const float*)d_in[12];

  float* out   = (float*)d_out;
  float* attnW = out + (long)4 * 1024 * 1024;

  char* ws = (char*)d_ws;
  u16*   qkvb   = (u16*)(ws);                    // [4096,3072] bf16
  u16*   vtb    = (u16*)(ws + 25165824);         // [64][64][1024]
  u16*   srcb   = (u16*)(ws + 33554432);
  u16*   ctxb   = (u16*)(ws + 41943040);
  u16*   xb     = (u16*)(ws + 50331648);
  u16*   w_in_b = (u16*)(ws + 58720256);
  u16*   w_outb = (u16*)(ws + 65011712);
  u16*   w1b    = (u16*)(ws + 67108864);
  u16*   w2b    = (u16*)(ws + 75497472);
  u16*   h1b    = (u16*)(ws);                    // [4096,4096] bf16 [0,32M)
  // split-K partials (fp32 element offsets from ws base)
  const long Q0 = 0,        Q1 = 4194304,  Q2 = 20971520, Q3 = 25165824;
  const long R0 = 8388608,  R1 = 14680064, R2 = 20971520, R3 = 25165824;
  float* wsf = (float*)ws;

  // 0. conversions
  cvt_all<<<dim3(8192), 256, 0, stream>>>(src, w_in, w_out, w1, w2,
                                          srcb, w_in_b, w_outb, w1b, w2b);

  // 1. qkvb = bf16(src @ w_in^T + b_in), q-cols scaled by 0.125
  gemm256<true><<<dim3(12, 16, 1), 512, 0, stream>>>(
      srcb, 1024, 0, w_in_b, 1024, 0, qkvb, 3072, 0, 0, 0, 0,
      b_in, 1024, 1024, 0.125f, 0);

  // 2. vtb = V^T per (b,h)
  transpose_v<<<dim3(1024), 256, 0, stream>>>(qkvb, vtb);

  // 3. fused attention: attnW fp32 + ctxb bf16
  attn_fused<<<dim3(512), 256, 0, stream>>>(qkvb, vtb, attnW, ctxb);

  // 4. out-proj, split-K=4 -> Q0..Q3
  gemm256<false><<<dim3(4, 16, 4), 512, 0, stream>>>(
      ctxb, 1024, 256, w_outb, 1024, 256, wsf, 1024, Q0, Q1, Q2, Q3,
      nullptr, 256, 0, 1.0f, 0);

  // 5. xb = bf16(LN1(Q0+Q1+Q2+Q3+src+b_out))
  ln_combine4<false><<<dim3(4096), 256, 0, stream>>>(
      wsf + Q0, wsf + Q1, wsf + Q2, wsf + Q3, src, b_out, g1, be1, nullptr, xb);

  // 6. h1b = bf16(relu(x @ w1^T + b1))
  gemm256<true><<<dim3(16, 16, 1), 512, 0, stream>>>(
      xb, 1024, 0, w1b, 1024, 0, h1b, 4096, 0, 0, 0, 0,
      b1, 1024, 0, 1.0f, 1);

  // 7. FFN2, split-K=4 -> R0..R3
  gemm256<false><<<dim3(4, 16, 4), 512, 0, stream>>>(
      h1b, 4096, 1024, w2b, 4096, 1024, wsf, 1024, R0, R1, R2, R3,
      nullptr, 1024, 0, 1.0f, 0);

  // 8. out = LN2(R0+R1+R2+R3+xb+b2)
  ln_combine4<true><<<dim3(4096), 256, 0, stream>>>(
      wsf + R0, wsf + R1, wsf + R2, wsf + R3, xb, b2, g2, be2, out, nullptr);
}

// Round 6
// 325.589 us; speedup vs baseline: 2.1885x; 1.0134x over previous
//
#include <hip/hip_runtime.h>

// ============================================================================
// EncoderLayerWithAttn — B=4, S=1024, D=1024, H=16, dh=64, DFF=4096
// d_out = [ out fp32 (4M) | attn_weights fp32 (64M) ]
//
// Round 5: gemm256 merged-phase schedule — ONE phase per BK=32 K-tile:
//   stage(t+2) -> 12 ds_read -> BAR -> lgkm0 -> 32 MFMA -> vmcnt(4) -> BAR
// Halves barrier rate vs round 4 (now matching the m201 template's 2 barriers
// per 16-MFMA-equivalent density), stage issued before ds_reads (T3 order).
// Ring-3 LDS, publish invariant (VM4 before closing BAR), swizzle unchanged.
// Everything else identical to round 4 (verified, absmax 0.03125).
//
// Workspace (112 MiB):
//   [0,24M)  qkvb bf16         -> Q0[0,16) Q1[16,32) -> h1b bf16 [0,32M)
//   [24,32M) vtb bf16
//   [32,40M) srcb bf16         -> R0 [32,48M)
//   [40,48M) ctxb bf16
//   [48,56M) xb bf16 (alive to end)
//   [56,62M) w_in_b  [62,64M) w_outb  [64,72M) w1b   -> R1 [56,72M)
//   [72,80M) w2b
//   [80,96M) Q2/R2   [96,112M) Q3/R3
// ============================================================================

#define DEVI __device__ __forceinline__

typedef __attribute__((ext_vector_type(4))) float f4;
typedef __attribute__((ext_vector_type(4))) float f32x4;
typedef __attribute__((ext_vector_type(8))) short s8;
typedef __attribute__((ext_vector_type(4))) unsigned short us4;
typedef unsigned short u16;

DEVI short bf16r(float f) {  // fp32 -> bf16 RNE
  unsigned u = __builtin_bit_cast(unsigned, f);
  unsigned r = (u + 0x7fffu + ((u >> 16) & 1u)) >> 16;
  return (short)(unsigned short)r;
}
DEVI float bf2f(u16 h) {
  unsigned u = ((unsigned)h) << 16;
  return __builtin_bit_cast(float, u);
}
DEVI s8 cvt8(f4 a, f4 b) {
  s8 r;
  r[0] = bf16r(a.x); r[1] = bf16r(a.y); r[2] = bf16r(a.z); r[3] = bf16r(a.w);
  r[4] = bf16r(b.x); r[5] = bf16r(b.y); r[6] = bf16r(b.z); r[7] = bf16r(b.w);
  return r;
}

DEVI void gload16(const void* g, void* l) {
  __builtin_amdgcn_global_load_lds(
      (const __attribute__((address_space(1))) unsigned int*)g,
      (__attribute__((address_space(3))) unsigned int*)l, 16, 0, 0);
}

#define BAR()   __builtin_amdgcn_s_barrier()
#define LGKM0() do { asm volatile("s_waitcnt lgkmcnt(0)" ::: "memory"); \
                     __builtin_amdgcn_sched_barrier(0); } while (0)
#define VM4()   do { asm volatile("s_waitcnt vmcnt(4)" ::: "memory"); \
                     __builtin_amdgcn_sched_barrier(0); } while (0)

// ---------------------------------------------------------------------------
// C[rows, cols] = A[rows,K]@B[cols,K]^T. 256x256 tile, 512 thr (8 waves 2Mx4N),
// BK=32, ring-3 LDS. ONE phase per K-tile: stage(t+2), 12 ds_read, BAR,
// lgkm0, 32 MFMA, VM4, BAR (publish). LDS rows 64B, granule swizzle
// phys = g ^ ((row>>1)&3) on both stage-source and ds_read.
template<bool OUTBF16>
__global__ __launch_bounds__(512, 2)
void gemm256(const u16* __restrict__ A, long lda, long sA,
             const u16* __restrict__ B, long ldb, long sB,
             void* __restrict__ Cp, long ldc,
             long c0, long c1, long c2, long c3,
             const float* __restrict__ bias, int K,
             int qcols, float qscale, int do_relu)
{
  __shared__ __align__(128) char LDS[98304];  // A: 3x16KB @0, B: 3x16KB @48K

  const int tid = threadIdx.x, lane = tid & 63, w = tid >> 6;
  const int wr = w >> 2, wc = w & 3;
  const int z = blockIdx.z;
  const int row0 = blockIdx.y * 256, col0 = blockIdx.x * 256;

  const u16* Ag = A + (long)z * sA + (long)row0 * lda;
  const u16* Bg = B + (long)z * sB + (long)col0 * ldb;
  long coff = (z == 0) ? c0 : (z == 1) ? c1 : (z == 2) ? c2 : c3;

  const int NT = K >> 5;

  // stage source lane mapping: row r = w*16 + (lane>>2), granule slot lane&3
  const int sr = (w << 4) + (lane >> 2);
  const int gsrc = (lane & 3) ^ ((sr >> 1) & 3);

  auto stageA = [&](int kt, int slot) {
#pragma unroll
    for (int h = 0; h < 2; ++h)
      gload16(Ag + (long)(h * 128 + sr) * lda + kt * 32 + gsrc * 8,
              LDS + slot * 16384 + h * 8192 + (w << 10));
  };
  auto stageB = [&](int kt, int slot) {
#pragma unroll
    for (int h = 0; h < 2; ++h)
      gload16(Bg + (long)(h * 128 + sr) * ldb + kt * 32 + gsrc * 8,
              LDS + 49152 + slot * 16384 + h * 8192 + (w << 10));
  };

  const int kg = lane >> 4, lr = lane & 15;
  auto rdA = [&](int buf, int fig, s8* aF) {
#pragma unroll
    for (int i = 0; i < 4; ++i) {
      int R = wr * 128 + (fig * 4 + i) * 16 + lr;
      aF[i] = *(const s8*)(LDS + buf * 16384 + R * 64 + ((kg ^ ((R >> 1) & 3)) << 4));
    }
  };
  auto rdB = [&](int buf, s8* bF) {
#pragma unroll
    for (int j = 0; j < 4; ++j) {
      int R = wc * 64 + j * 16 + lr;
      bF[j] = *(const s8*)(LDS + 49152 + buf * 16384 + R * 64 + ((kg ^ ((R >> 1) & 3)) << 4));
    }
  };

  f32x4 acc[8][4] = {};

  // prologue: stage tiles 0,1; publish tile 0 (VM4 -> BAR) before first read
  stageA(0, 0); stageB(0, 0);
  stageA(1, 1); stageB(1, 1);
  VM4();
  BAR();

  int buf = 0;
  for (int t = 0; t < NT; ++t) {
    int nbuf = buf + 2; if (nbuf >= 3) nbuf -= 3;
    int tc = (t + 2 < NT) ? t + 2 : NT - 1;
    s8 aF0[4], aF1[4], bF[4];

    // ---- single phase: stage(t+2) first, then all 12 ds_reads ----
    stageA(tc, nbuf);
    stageB(tc, nbuf);
    rdB(buf, bF);
    rdA(buf, 0, aF0);
    rdA(buf, 1, aF1);
    BAR();
    LGKM0();
    __builtin_amdgcn_s_setprio(1);
#pragma unroll
    for (int i = 0; i < 4; ++i)
#pragma unroll
      for (int j = 0; j < 4; ++j)
        acc[i][j] = __builtin_amdgcn_mfma_f32_16x16x32_bf16(aF0[i], bF[j], acc[i][j], 0, 0, 0);
#pragma unroll
    for (int i = 0; i < 4; ++i)
#pragma unroll
      for (int j = 0; j < 4; ++j)
        acc[4 + i][j] = __builtin_amdgcn_mfma_f32_16x16x32_bf16(aF1[i], bF[j], acc[4 + i][j], 0, 0, 0);
    __builtin_amdgcn_s_setprio(0);
    VM4();   // certify tile t+1's loads retired (this wave) ...
    BAR();   // ... then publish to all waves; t+1 reads are now safe
    buf = (buf == 2) ? 0 : buf + 1;
  }
  asm volatile("s_waitcnt vmcnt(0)" ::: "memory");

  // ---- epilogue: C/D layout col=lane&15, row=(lane>>4)*4+q ----
  float* Cf = (float*)Cp + coff;
  u16*   Cb = (u16*)Cp + coff;
#pragma unroll
  for (int fi = 0; fi < 8; ++fi) {
#pragma unroll
    for (int fj = 0; fj < 4; ++fj) {
      int rb = row0 + wr * 128 + fi * 16 + (lane >> 4) * 4;
      int c  = col0 + wc * 64 + fj * 16 + lr;
      float bv = bias ? bias[c] : 0.0f;
      float sc = (c < qcols) ? qscale : 1.0f;
#pragma unroll
      for (int q = 0; q < 4; ++q) {
        float v = (acc[fi][fj][q] + bv) * sc;
        if (do_relu) v = fmaxf(v, 0.0f);
        long idx = (long)(rb + q) * ldc + c;
        if constexpr (OUTBF16) Cb[idx] = (u16)bf16r(v);
        else                   Cf[idx] = v;
      }
    }
  }
}

// ---------------------------------------------------------------------------
// Fused attention (round-2 verified, unchanged).
__global__ __launch_bounds__(256)
void attn_fused(const u16* __restrict__ qkvb, const u16* __restrict__ vtb,
                float* __restrict__ attnW, u16* __restrict__ ctxb)
{
  __shared__ __align__(128) u16 Kt[128 * 64];
  __shared__ __align__(128) u16 Vt[64 * 128];
  __shared__ __align__(128) u16 Pt[4 * 32 * 128];

  int blk = blockIdx.x;
  int bh = blk >> 3, qt = blk & 7;
  int b = bh >> 4, h = bh & 15;
  int tid = threadIdx.x, lane = tid & 63, w = tid >> 6;

  const u16* Qg = qkvb + (long)b * 3145728 + (long)(qt * 128) * 3072 + h * 64;
#pragma unroll
  for (int c = 0; c < 4; ++c) {
    int seg = w * 4 + c;
    int r = seg * 8 + (lane >> 3);
    int g = (lane & 7) ^ (r & 7);
    gload16(Qg + (long)r * 3072 + g * 8, (char*)Kt + seg * 1024);
  }
  __syncthreads();
  s8 aq[2][2];
#pragma unroll
  for (int i = 0; i < 2; ++i)
#pragma unroll
    for (int kk = 0; kk < 2; ++kk) {
      int R = w * 32 + i * 16 + (lane & 15);
      int kgq = kk * 4 + (lane >> 4);
      aq[i][kk] = *(const s8*)((char*)Kt + R * 128 + ((kgq ^ (R & 7)) * 16));
    }

  const u16* Kbase = qkvb + (long)b * 3145728 + 1024 + h * 64;
  const u16* Vbase = vtb + (long)bh * 65536;

  float m[2][4], l[2][4];
#pragma unroll
  for (int i = 0; i < 2; ++i)
#pragma unroll
    for (int q = 0; q < 4; ++q) { m[i][q] = -1e30f; l[i][q] = 0.0f; }

  // ===== pass 1: running max + denom =====
  for (int kc = 0; kc < 8; ++kc) {
    __syncthreads();
#pragma unroll
    for (int c = 0; c < 4; ++c) {
      int seg = w * 4 + c;
      int r = seg * 8 + (lane >> 3);
      int g = (lane & 7) ^ (r & 7);
      gload16(Kbase + (long)(kc * 128 + r) * 3072 + g * 8, (char*)Kt + seg * 1024);
    }
    __syncthreads();

    f32x4 s[2][8] = {};
#pragma unroll
    for (int kk = 0; kk < 2; ++kk) {
      s8 bk[8];
      int kgq = kk * 4 + (lane >> 4);
#pragma unroll
      for (int j = 0; j < 8; ++j) {
        int R = j * 16 + (lane & 15);
        bk[j] = *(const s8*)((char*)Kt + R * 128 + ((kgq ^ (R & 7)) * 16));
      }
#pragma unroll
      for (int i = 0; i < 2; ++i)
#pragma unroll
        for (int j = 0; j < 8; ++j)
          s[i][j] = __builtin_amdgcn_mfma_f32_16x16x32_bf16(aq[i][kk], bk[j], s[i][j], 0, 0, 0);
    }

#pragma unroll
    for (int i = 0; i < 2; ++i)
#pragma unroll
      for (int q = 0; q < 4; ++q) {
        float mx = s[i][0][q];
#pragma unroll
        for (int j = 1; j < 8; ++j) mx = fmaxf(mx, s[i][j][q]);
        mx = fmaxf(mx, __shfl_xor(mx, 1));
        mx = fmaxf(mx, __shfl_xor(mx, 2));
        mx = fmaxf(mx, __shfl_xor(mx, 4));
        mx = fmaxf(mx, __shfl_xor(mx, 8));
        float mn = fmaxf(m[i][q], mx);
        float sum = 0.0f;
#pragma unroll
        for (int j = 0; j < 8; ++j) sum += __expf(s[i][j][q] - mn);
        sum += __shfl_xor(sum, 1);
        sum += __shfl_xor(sum, 2);
        sum += __shfl_xor(sum, 4);
        sum += __shfl_xor(sum, 8);
        l[i][q] = l[i][q] * __expf(m[i][q] - mn) + sum;
        m[i][q] = mn;
      }
  }

  float inv[2][4];
#pragma unroll
  for (int i = 0; i < 2; ++i)
#pragma unroll
    for (int q = 0; q < 4; ++q) inv[i][q] = 1.0f / l[i][q];

  // ===== pass 2: P write + PV =====
  f32x4 o_[2][4] = {};
  float* aw = attnW + (long)bh * 1048576 + (long)(qt * 128) * 1024;
  u16* Pw = Pt + w * 4096;

  for (int kc = 0; kc < 8; ++kc) {
    __syncthreads();
#pragma unroll
    for (int c = 0; c < 4; ++c) {
      int seg = w * 4 + c;
      int r = seg * 8 + (lane >> 3);
      int g = (lane & 7) ^ (r & 7);
      gload16(Kbase + (long)(kc * 128 + r) * 3072 + g * 8, (char*)Kt + seg * 1024);
    }
#pragma unroll
    for (int c = 0; c < 4; ++c) {
      int seg = w * 4 + c;
      int r = seg * 4 + (lane >> 4);
      int g = (lane & 15) ^ (r & 7);
      gload16(Vbase + (long)r * 1024 + kc * 128 + g * 8, (char*)Vt + seg * 1024);
    }
    __syncthreads();

    f32x4 s[2][8] = {};
#pragma unroll
    for (int kk = 0; kk < 2; ++kk) {
      s8 bk[8];
      int kgq = kk * 4 + (lane >> 4);
#pragma unroll
      for (int j = 0; j < 8; ++j) {
        int R = j * 16 + (lane & 15);
        bk[j] = *(const s8*)((char*)Kt + R * 128 + ((kgq ^ (R & 7)) * 16));
      }
#pragma unroll
      for (int i = 0; i < 2; ++i)
#pragma unroll
        for (int j = 0; j < 8; ++j)
          s[i][j] = __builtin_amdgcn_mfma_f32_16x16x32_bf16(aq[i][kk], bk[j], s[i][j], 0, 0, 0);
    }

#pragma unroll
    for (int i = 0; i < 2; ++i)
#pragma unroll
      for (int j = 0; j < 8; ++j)
#pragma unroll
        for (int q = 0; q < 4; ++q) {
          float p = __expf(s[i][j][q] - m[i][q]) * inv[i][q];
          int R = i * 16 + (lane >> 4) * 4 + q;
          int C = j * 16 + (lane & 15);
          aw[(long)(w * 32 + R) * 1024 + kc * 128 + C] = p;
          *(u16*)((char*)Pw + R * 256 + (((C >> 3) ^ (R & 7)) * 16) + (C & 7) * 2)
              = (u16)bf16r(p);
        }

#pragma unroll
    for (int kks = 0; kks < 4; ++kks) {
      int kgq = kks * 4 + (lane >> 4);
      s8 pa[2], bv[4];
#pragma unroll
      for (int i = 0; i < 2; ++i) {
        int R = i * 16 + (lane & 15);
        pa[i] = *(const s8*)((char*)Pw + R * 256 + ((kgq ^ (R & 7)) * 16));
      }
#pragma unroll
      for (int j = 0; j < 4; ++j) {
        int R = j * 16 + (lane & 15);
        bv[j] = *(const s8*)((char*)Vt + R * 256 + ((kgq ^ (R & 7)) * 16));
      }
#pragma unroll
      for (int i = 0; i < 2; ++i)
#pragma unroll
        for (int j = 0; j < 4; ++j)
          o_[i][j] = __builtin_amdgcn_mfma_f32_16x16x32_bf16(pa[i], bv[j], o_[i][j], 0, 0, 0);
    }
  }

#pragma unroll
  for (int i = 0; i < 2; ++i)
#pragma unroll
    for (int j = 0; j < 4; ++j)
#pragma unroll
      for (int q = 0; q < 4; ++q) {
        int R = w * 32 + i * 16 + (lane >> 4) * 4 + q;
        int col = h * 64 + j * 16 + (lane & 15);
        ctxb[(long)(b * 1024 + qt * 128 + R) * 1024 + col] = (u16)bf16r(o_[i][j][q]);
      }
}

// ---------------------------------------------------------------------------
DEVI float blockSum(float v, float* sh) {
#pragma unroll
  for (int o = 32; o > 0; o >>= 1) v += __shfl_xor(v, o);
  int w = threadIdx.x >> 6;
  __syncthreads();
  if ((threadIdx.x & 63) == 0) sh[w] = v;
  __syncthreads();
  return (sh[0] + sh[1]) + (sh[2] + sh[3]);
}

// in = P0+P1+P2+P3 + resid + bias[c]; LayerNorm(g,be); write fp32 and/or bf16
template<bool RBF16>
__global__ __launch_bounds__(256)
void ln_combine4(const float* __restrict__ P0, const float* __restrict__ P1,
                 const float* __restrict__ P2, const float* __restrict__ P3,
                 const void* __restrict__ resid, const float* __restrict__ bias,
                 const float* __restrict__ g, const float* __restrict__ be,
                 float* __restrict__ outf, u16* __restrict__ outb)
{
  __shared__ float sh[4];
  long row = blockIdx.x;
  int t = threadIdx.x;
  long off = row * 1024 + t * 4;
  f4 v = *(const f4*)(P0 + off);
  v += *(const f4*)(P1 + off);
  v += *(const f4*)(P2 + off);
  v += *(const f4*)(P3 + off);
  if constexpr (RBF16) {
    us4 rp = *(const us4*)((const u16*)resid + off);
    v.x += bf2f(rp.x); v.y += bf2f(rp.y); v.z += bf2f(rp.z); v.w += bf2f(rp.w);
  } else {
    v += *(const f4*)((const float*)resid + off);
  }
  v += *(const f4*)(bias + t * 4);
  float s = (v.x + v.y) + (v.z + v.w);
  s = blockSum(s, sh);
  float mu = s * (1.0f / 1024.0f);
  f4 d = v - mu;
  float s2 = (d.x * d.x + d.y * d.y) + (d.z * d.z + d.w * d.w);
  s2 = blockSum(s2, sh);
  float rs = rsqrtf(s2 * (1.0f / 1024.0f) + 1e-5f);
  f4 gg = *(const f4*)(g + t * 4);
  f4 bb = *(const f4*)(be + t * 4);
  f4 o = d * rs * gg + bb;
  if (outf) *(f4*)(outf + off) = o;
  if (outb) {
    us4 ob;
    ob.x = (u16)bf16r(o.x); ob.y = (u16)bf16r(o.y);
    ob.z = (u16)bf16r(o.z); ob.w = (u16)bf16r(o.w);
    *(us4*)(outb + off) = ob;
  }
}

// all five fp32->bf16 conversions in one launch
__global__ __launch_bounds__(256)
void cvt_all(const float* __restrict__ s0, const float* __restrict__ s1,
             const float* __restrict__ s2, const float* __restrict__ s3,
             const float* __restrict__ s4,
             u16* __restrict__ d0, u16* __restrict__ d1, u16* __restrict__ d2,
             u16* __restrict__ d3, u16* __restrict__ d4)
{
  int bi = blockIdx.x;
  const float* s; u16* d; int base;
  if      (bi < 2048) { s = s0; d = d0; base = bi; }
  else if (bi < 3584) { s = s1; d = d1; base = bi - 2048; }
  else if (bi < 4096) { s = s2; d = d2; base = bi - 3584; }
  else if (bi < 6144) { s = s3; d = d3; base = bi - 4096; }
  else                { s = s4; d = d4; base = bi - 6144; }
  long i = ((long)base * 256 + threadIdx.x) * 8;
  f4 a = *(const f4*)(s + i);
  f4 b = *(const f4*)(s + i + 4);
  *(s8*)(d + i) = cvt8(a, b);
}

// vt[bh][d][s] = qkvb[b, s, 2048 + h*64 + d]   (bf16)
__global__ __launch_bounds__(256)
void transpose_v(const u16* __restrict__ qkv, u16* __restrict__ vt) {
  __shared__ u16 tile[64][72];
  int blk = blockIdx.x, bh = blk >> 4, st = blk & 15;
  int b = bh >> 4, h = bh & 15, s0 = st * 64;
  const u16* gq = qkv + (long)b * 1024 * 3072 + 2048 + (long)h * 64;
  int t = threadIdx.x;
  int sl = t >> 4, dq = (t & 15) * 4;
#pragma unroll
  for (int it = 0; it < 4; ++it) {
    int s = it * 16 + sl;
    us4 v = *(const us4*)(gq + (long)(s0 + s) * 3072 + dq);
    tile[dq + 0][s] = v.x; tile[dq + 1][s] = v.y;
    tile[dq + 2][s] = v.z; tile[dq + 3][s] = v.w;
  }
  __syncthreads();
  u16* o = vt + (long)bh * 65536 + s0;
  int dl = t >> 4, sq = (t & 15) * 4;
#pragma unroll
  for (int it = 0; it < 4; ++it) {
    int d = it * 16 + dl;
    us4 v;
    v.x = tile[d][sq + 0]; v.y = tile[d][sq + 1];
    v.z = tile[d][sq + 2]; v.w = tile[d][sq + 3];
    *(us4*)(o + (long)d * 1024 + sq) = v;
  }
}

// ============================================================================
extern "C" void kernel_launch(void* const* d_in, const int* in_sizes, int n_in,
                              void* d_out, int out_size, void* d_ws, size_t ws_size,
                              hipStream_t stream)
{
  (void)in_sizes; (void)n_in; (void)out_size; (void)ws_size;
  const float* src   = (const float*)d_in[0];
  const float* w_in  = (const float*)d_in[1];
  const float* b_in  = (const float*)d_in[2];
  const float* w_out = (const float*)d_in[3];
  const float* b_out = (const float*)d_in[4];
  const float* w1    = (const float*)d_in[5];
  const float* b1    = (const float*)d_in[6];
  const float* w2    = (const float*)d_in[7];
  const float* b2    = (const float*)d_in[8];
  const float* g1    = (const float*)d_in[9];
  const float* be1   = (const float*)d_in[10];
  const float* g2    = (const float*)d_in[11];
  const float* be2   = (const float*)d_in[12];

  float* out   = (float*)d_out;
  float* attnW = out + (long)4 * 1024 * 1024;

  char* ws = (char*)d_ws;
  u16*   qkvb   = (u16*)(ws);                    // [4096,3072] bf16
  u16*   vtb    = (u16*)(ws + 25165824);         // [64][64][1024]
  u16*   srcb   = (u16*)(ws + 33554432);
  u16*   ctxb   = (u16*)(ws + 41943040);
  u16*   xb     = (u16*)(ws + 50331648);
  u16*   w_in_b = (u16*)(ws + 58720256);
  u16*   w_outb = (u16*)(ws + 65011712);
  u16*   w1b    = (u16*)(ws + 67108864);
  u16*   w2b    = (u16*)(ws + 75497472);
  u16*   h1b    = (u16*)(ws);                    // [4096,4096] bf16 [0,32M)
  // split-K partials (fp32 element offsets from ws base)
  const long Q0 = 0,        Q1 = 4194304,  Q2 = 20971520, Q3 = 25165824;
  const long R0 = 8388608,  R1 = 14680064, R2 = 20971520, R3 = 25165824;
  float* wsf = (float*)ws;

  // 0. conversions
  cvt_all<<<dim3(8192), 256, 0, stream>>>(src, w_in, w_out, w1, w2,
                                          srcb, w_in_b, w_outb, w1b, w2b);

  // 1. qkvb = bf16(src @ w_in^T + b_in), q-cols scaled by 0.125
  gemm256<true><<<dim3(12, 16, 1), 512, 0, stream>>>(
      srcb, 1024, 0, w_in_b, 1024, 0, qkvb, 3072, 0, 0, 0, 0,
      b_in, 1024, 1024, 0.125f, 0);

  // 2. vtb = V^T per (b,h)
  transpose_v<<<dim3(1024), 256, 0, stream>>>(qkvb, vtb);

  // 3. fused attention: attnW fp32 + ctxb bf16
  attn_fused<<<dim3(512), 256, 0, stream>>>(qkvb, vtb, attnW, ctxb);

  // 4. out-proj, split-K=4 -> Q0..Q3
  gemm256<false><<<dim3(4, 16, 4), 512, 0, stream>>>(
      ctxb, 1024, 256, w_outb, 1024, 256, wsf, 1024, Q0, Q1, Q2, Q3,
      nullptr, 256, 0, 1.0f, 0);

  // 5. xb = bf16(LN1(Q0+Q1+Q2+Q3+src+b_out))
  ln_combine4<false><<<dim3(4096), 256, 0, stream>>>(
      wsf + Q0, wsf + Q1, wsf + Q2, wsf + Q3, src, b_out, g1, be1, nullptr, xb);

  // 6. h1b = bf16(relu(x @ w1^T + b1))
  gemm256<true><<<dim3(16, 16, 1), 512, 0, stream>>>(
      xb, 1024, 0, w1b, 1024, 0, h1b, 4096, 0, 0, 0, 0,
      b1, 1024, 0, 1.0f, 1);

  // 7. FFN2, split-K=4 -> R0..R3
  gemm256<false><<<dim3(4, 16, 4), 512, 0, stream>>>(
      h1b, 4096, 1024, w2b, 4096, 1024, wsf, 1024, R0, R1, R2, R3,
      nullptr, 1024, 0, 1.0f, 0);

  // 8. out = LN2(R0+R1+R2+R3+xb+b2)
  ln_combine4<true><<<dim3(4096), 256, 0, stream>>>(
      wsf + R0, wsf + R1, wsf + R2, wsf + R3, xb, b2, g2, be2, out, nullptr);
}